// Round 1
// baseline (3939.553 us; speedup 1.0000x reference)
//
#include <hip/hip_runtime.h>

#define SEQ  2048
#define NB   8
#define HD   256
#define G3   768
#define NV   100

typedef float f32x4 __attribute__((ext_vector_type(4)));
typedef int   i32x4 __attribute__((ext_vector_type(4)));

#define INV26 1.490116119384765625e-8f   // 2^-26

__device__ __forceinline__ float sigm(float x) {
  x = fminf(fmaxf(x, -30.f), 30.f);
  return 1.f / (1.f + __expf(-x));
}
__device__ __forceinline__ float tanh_fast(float x) {
  x = fminf(fmaxf(x, -15.f), 15.f);
  float e = __expf(2.f * x);
  return (e - 1.f) / (e + 1.f);
}

// ---------------- K1: xg lookup table: table[v][g] = emb[v]·w_ih[g] + b_ih[g]
__global__ __launch_bounds__(256) void build_table(
    const float* __restrict__ emb, const float* __restrict__ w_ih,
    const float* __restrict__ b_ih, float* __restrict__ table) {
  __shared__ float eL[256];
  __shared__ float wL[256][37];
  int v = blockIdx.x, tid = threadIdx.x;
  eL[tid] = emb[v * HD + tid];
  for (int gt = 0; gt < 3; ++gt) {
    float acc = b_ih[gt * 256 + tid];
    for (int e0 = 0; e0 < HD; e0 += 32) {
      __syncthreads();
      #pragma unroll
      for (int i = 0; i < 32; ++i) {
        int idx = tid + i * 256;
        int r = idx >> 5, c = idx & 31;
        wL[r][c] = w_ih[(size_t)(gt * 256 + r) * HD + e0 + c];
      }
      __syncthreads();
      #pragma unroll
      for (int c = 0; c < 32; ++c) acc += eL[e0 + c] * wL[tid][c];
    }
    table[(size_t)v * G3 + gt * 256 + tid] = acc;
  }
}

// ---------------- K2: ALL-8-BATCH fused GRU scan: ONE workgroup, 16 waves.
// Key idea: all batches share w_hh, so the 8 independent recurrences fill the
// MFMA M-dim: A rows 2b = hi8 plane of batch b, rows 2b+1 = lou-128 plane
// (8 batches x 2 planes = 16 rows). The same 192 i8 MFMAs/step that one WG
// previously spent on ONE batch now serve all 8 -> 8x less matrix-pipe work.
// Wave wv owns hidden units j = wv*16+ncol and holds the r/z/n weight rows for
// them (48 VGPRs), so after its own 12 MFMAs each lane has all 3 gates for
// batches 2*quad, 2*quad+1 in-register (C/D: col=lane&15, row=(lane>>4)*4+reg
// -> acc regs (0,1)/(2,3) are that lane's (hi,lo) pairs; no shfl needed).
// hg LDS buffer + its barrier are gone; hpk is double-buffered so the step has
// ONE barrier. Verified i8 math (prior rounds): q_w = round(w*2^11);
// hg = (256*D_hi + D_lo + 128*sum_k q_w) * 2^-26 + b_hh.
__global__ void __launch_bounds__(1024) gru_scan(
    const int* __restrict__ x, const float* __restrict__ w_hh,
    const float* __restrict__ b_hh, const float* __restrict__ table,
    float* __restrict__ all_h, float* __restrict__ h_last) {
  __shared__ __align__(16) signed char hpk[2][16 * 272];
  int tid = threadIdx.x;
  int lane = tid & 63, wv = tid >> 6;       // 16 waves
  int ncol = lane & 15, quad = lane >> 4;
  int j = wv * 16 + ncol;                   // this lane's hidden unit

  // init buffer 0 for h=0: even rows (hi8)=0, odd rows (lou-128)=-128
  for (int i = tid; i < 16 * 272; i += 1024)
    hpk[0][i] = ((i / 272) & 1) ? (signed char)-128 : 0;

  // quantize weights into registers; wave wv owns rows j, 256+j, 512+j
  i32x4 bw[3][4];
  float Cn[3];
  #pragma unroll
  for (int t3 = 0; t3 < 3; ++t3) {
    int row = t3 * 256 + j;
    int sw = 0;
    #pragma unroll
    for (int c = 0; c < 4; ++c) {
      const float* p = w_hh + (size_t)row * HD + c * 64 + quad * 16;
      unsigned pw[4] = {0u, 0u, 0u, 0u};
      #pragma unroll
      for (int e = 0; e < 16; ++e) {
        int q = __float2int_rn(p[e] * 2048.f);       // w * 2^11
        q = max(-127, min(127, q));
        sw += q;
        pw[e >> 2] |= ((unsigned)(q & 255)) << ((e & 3) * 8);
      }
      bw[t3][c] = (i32x4){(int)pw[0], (int)pw[1], (int)pw[2], (int)pw[3]};
    }
    sw += __shfl_xor(sw, 16);
    sw += __shfl_xor(sw, 32);                        // full-K sum of q_w for row
    Cn[t3] = b_hh[row] + 128.f * (float)sw * INV26;
  }

  // per-lane gate state for batches b = 2*quad + i (i = 0,1), unit j
  float hreg[2] = {0.f, 0.f};
  float xr[2], xz[2], xn[2];
  {
    int v0 = x[(2 * quad) * SEQ];
    int v1 = x[(2 * quad + 1) * SEQ];
    const float* t0 = table + (size_t)v0 * G3 + j;
    const float* t1 = table + (size_t)v1 * G3 + j;
    xr[0] = t0[0]; xz[0] = t0[256]; xn[0] = t0[512];
    xr[1] = t1[0]; xz[1] = t1[256]; xn[1] = t1[512];
  }

  int a_base = ncol * 272 + quad * 16;
  __syncthreads();                                   // hpk[0] init visible

  for (int t = 0; t < SEQ; ++t) {
    const signed char* cb = hpk[t & 1];
    signed char* nxt = hpk[(t + 1) & 1];
    i32x4 a[4];
    #pragma unroll
    for (int c = 0; c < 4; ++c)
      a[c] = *(const i32x4*)&cb[a_base + c * 64];
    float hg[3][2];
    #pragma unroll
    for (int t3 = 0; t3 < 3; ++t3) {
      i32x4 acc = {0, 0, 0, 0};
      #pragma unroll
      for (int c = 0; c < 4; ++c)
        acc = __builtin_amdgcn_mfma_i32_16x16x64_i8(a[c], bw[t3][c], acc, 0, 0, 0);
      // acc reg r = D row 4*quad+r: (hi,lo) of batch 2*quad at regs (0,1),
      // (hi,lo) of batch 2*quad+1 at regs (2,3)
      hg[t3][0] = ((float)acc[0] * 256.f + (float)acc[1]) * INV26 + Cn[t3];
      hg[t3][1] = ((float)acc[2] * 256.f + (float)acc[3]) * INV26 + Cn[t3];
    }
    int tn = (t + 1 < SEQ) ? t + 1 : t;              // prefetch next step's xg
    #pragma unroll
    for (int i = 0; i < 2; ++i) {
      int b = 2 * quad + i;
      float r = sigm(xr[i] + hg[0][i]);
      float z = sigm(xz[i] + hg[1][i]);
      float n = tanh_fast(xn[i] + r * hg[2][i]);
      float h = (1.f - z) * n + z * hreg[i];
      hreg[i] = h;
      int q = min(__float2int_rn(h * 32768.f), 32767);
      int lou = q & 255;
      int hi8 = (q - lou) >> 8;
      nxt[(2 * b) * 272 + j] = (signed char)hi8;
      nxt[(2 * b + 1) * 272 + j] = (signed char)(lou - 128);
      all_h[((size_t)b * SEQ + t) * HD + j] = h;
      int v = x[b * SEQ + tn];
      const float* tr = table + (size_t)v * G3 + j;
      xr[i] = tr[0]; xz[i] = tr[256]; xn[i] = tr[512];
    }
    __syncthreads();                                 // nxt complete -> next step
  }
  #pragma unroll
  for (int i = 0; i < 2; ++i)
    h_last[(2 * quad + i) * HD + j] = hreg[i];
}

// ---------------- generic f32 GEMM  C[M,N] = A[M,K]·W[N,K]^T + bias
template<int ACT>
__global__ __launch_bounds__(256) void gemm_bias(
    const float* __restrict__ A, int lda,
    const float* __restrict__ W, const float* __restrict__ bias,
    float* __restrict__ C, int ldc, int N, int K) {
  __shared__ float As[128][36];
  __shared__ float Ws[64][36];
  int tid = threadIdx.x;
  int m0 = blockIdx.y * 128, n0 = blockIdx.x * 64;
  int ml = tid & 31, g = tid >> 5;
  float acc[4][8];
  #pragma unroll
  for (int i = 0; i < 4; ++i)
    #pragma unroll
    for (int jj = 0; jj < 8; ++jj) acc[i][jj] = 0.f;
  for (int k0 = 0; k0 < K; k0 += 32) {
    __syncthreads();
    #pragma unroll
    for (int i = 0; i < 4; ++i) {
      int idx = tid + i * 256;
      int r = idx >> 3, c4 = (idx & 7) * 4;
      *(f32x4*)&As[r][c4] = *(const f32x4*)&A[(size_t)(m0 + r) * lda + k0 + c4];
    }
    #pragma unroll
    for (int i = 0; i < 2; ++i) {
      int idx = tid + i * 256;
      int r = idx >> 3, c4 = (idx & 7) * 4;
      f32x4 wv = {0.f, 0.f, 0.f, 0.f};
      if (n0 + r < N) wv = *(const f32x4*)&W[(size_t)(n0 + r) * K + k0 + c4];
      *(f32x4*)&Ws[r][c4] = wv;
    }
    __syncthreads();
    #pragma unroll
    for (int k4 = 0; k4 < 32; k4 += 4) {
      f32x4 av[4], wv8[8];
      #pragma unroll
      for (int i = 0; i < 4; ++i) av[i] = *(const f32x4*)&As[ml + i * 32][k4];
      #pragma unroll
      for (int jj = 0; jj < 8; ++jj) wv8[jj] = *(const f32x4*)&Ws[g * 8 + jj][k4];
      #pragma unroll
      for (int kk = 0; kk < 4; ++kk)
        #pragma unroll
        for (int i = 0; i < 4; ++i)
          #pragma unroll
          for (int jj = 0; jj < 8; ++jj)
            acc[i][jj] += av[i][kk] * wv8[jj][kk];
    }
  }
  #pragma unroll
  for (int i = 0; i < 4; ++i) {
    int m = m0 + ml + i * 32;
    #pragma unroll
    for (int jj = 0; jj < 8; ++jj) {
      int n = n0 + g * 8 + jj;
      if (n < N) {
        float val = acc[i][jj] + bias[n];
        if (ACT) val = tanh_fast(val);
        C[(size_t)m * ldc + n] = val;
      }
    }
  }
}

// ---------------- comb GEMM: A = [all_h | ctx] split-K (K=512), tanh epilogue
__global__ __launch_bounds__(256) void gemm_bias_cat(
    const float* __restrict__ A1, const float* __restrict__ A2,
    const float* __restrict__ W, const float* __restrict__ bias,
    float* __restrict__ C) {
  __shared__ float As[128][36];
  __shared__ float Ws[64][36];
  const int K = 512;
  int tid = threadIdx.x;
  int m0 = blockIdx.y * 128, n0 = blockIdx.x * 64;
  int ml = tid & 31, g = tid >> 5;
  float acc[4][8];
  #pragma unroll
  for (int i = 0; i < 4; ++i)
    #pragma unroll
    for (int jj = 0; jj < 8; ++jj) acc[i][jj] = 0.f;
  for (int k0 = 0; k0 < K; k0 += 32) {
    const float* src = (k0 < 256) ? A1 : A2;
    int kb = (k0 < 256) ? k0 : k0 - 256;
    __syncthreads();
    #pragma unroll
    for (int i = 0; i < 4; ++i) {
      int idx = tid + i * 256;
      int r = idx >> 3, c4 = (idx & 7) * 4;
      *(f32x4*)&As[r][c4] = *(const f32x4*)&src[(size_t)(m0 + r) * 256 + kb + c4];
    }
    #pragma unroll
    for (int i = 0; i < 2; ++i) {
      int idx = tid + i * 256;
      int r = idx >> 3, c4 = (idx & 7) * 4;
      *(f32x4*)&Ws[r][c4] = *(const f32x4*)&W[(size_t)(n0 + r) * K + k0 + c4];
    }
    __syncthreads();
    #pragma unroll
    for (int k4 = 0; k4 < 32; k4 += 4) {
      f32x4 av[4], wv8[8];
      #pragma unroll
      for (int i = 0; i < 4; ++i) av[i] = *(const f32x4*)&As[ml + i * 32][k4];
      #pragma unroll
      for (int jj = 0; jj < 8; ++jj) wv8[jj] = *(const f32x4*)&Ws[g * 8 + jj][k4];
      #pragma unroll
      for (int kk = 0; kk < 4; ++kk)
        #pragma unroll
        for (int i = 0; i < 4; ++i)
          #pragma unroll
          for (int jj = 0; jj < 8; ++jj)
            acc[i][jj] += av[i][kk] * wv8[jj][kk];
    }
  }
  #pragma unroll
  for (int i = 0; i < 4; ++i) {
    int m = m0 + ml + i * 32;
    #pragma unroll
    for (int jj = 0; jj < 8; ++jj) {
      int n = n0 + g * 8 + jj;
      C[(size_t)m * 256 + n] = tanh_fast(acc[i][jj] + bias[n]);
    }
  }
}

// ---------------- K4: causal flash attention, q-tile 32 / k-tile 16, all f32.
// Qs/Ks XOR-swizzled -> conflict-free score loop.
__global__ __launch_bounds__(256) void attention_kernel(
    const float* __restrict__ all_h, const float* __restrict__ keys,
    float* __restrict__ ctx) {
  __shared__ float Qs[32 * 256];
  __shared__ float Ks[16 * 256];
  __shared__ float Hs[16 * 256];
  __shared__ float Sl[32][17];
  __shared__ float mL[32], lL[32], aL[32];
  int b = blockIdx.y, jb = blockIdx.x, tid = threadIdx.x;
  const float* hb = all_h + (size_t)b * SEQ * HD;
  const float* kb = keys  + (size_t)b * SEQ * HD;
  int qg = tid & 15, hi = tid >> 4;
  int r0 = qg * 2, r1 = r0 + 1;
  int sq = qg & 7;                          // Q swizzle bits for rows r0,r1
  for (int phase = 0; phase < 2; ++phase) {
    int qt = phase ? (63 - jb) : jb;
    int q0 = qt * 32;
    __syncthreads();
    #pragma unroll
    for (int i = 0; i < 8; ++i) {           // stage Q 32x256 (swizzled)
      int idx = tid + i * 256;
      int r = idx >> 6, cg = idx & 63;
      *(f32x4*)&Qs[r * 256 + ((cg ^ ((r >> 1) & 7)) << 2)] =
          *(const f32x4*)&hb[(size_t)(q0 + r) * HD + cg * 4];
    }
    if (tid < 32) { mL[tid] = -3e38f; lL[tid] = 0.f; }
    float O0[16], O1[16];
    #pragma unroll
    for (int c = 0; c < 16; ++c) { O0[c] = 0.f; O1[c] = 0.f; }
    int nkt = 2 * (qt + 1);
    for (int kt = 0; kt < nkt; ++kt) {
      int k0 = kt * 16;
      __syncthreads();
      #pragma unroll
      for (int i = 0; i < 4; ++i) {         // stage K (swizzled) + V, 16x256 each
        int idx = tid + i * 256;
        int r = idx >> 6, cg = idx & 63;
        *(f32x4*)&Ks[r * 256 + ((cg ^ (r & 7)) << 2)] =
            *(const f32x4*)&kb[(size_t)(k0 + r) * HD + cg * 4];
        *(f32x4*)&Hs[r * 256 + cg * 4] = *(const f32x4*)&hb[(size_t)(k0 + r) * HD + cg * 4];
      }
      __syncthreads();
      int kc = hi;
      int sk = kc & 7;
      float sc0 = 0.f, sc1 = 0.f;
      #pragma unroll 8
      for (int c = 0; c < 64; ++c) {
        f32x4 kv  = *(const f32x4*)&Ks[kc * 256 + ((c ^ sk) << 2)];
        f32x4 q0v = *(const f32x4*)&Qs[r0 * 256 + ((c ^ sq) << 2)];
        f32x4 q1v = *(const f32x4*)&Qs[r1 * 256 + ((c ^ sq) << 2)];
        sc0 += q0v[0]*kv[0] + q0v[1]*kv[1] + q0v[2]*kv[2] + q0v[3]*kv[3];
        sc1 += q1v[0]*kv[0] + q1v[1]*kv[1] + q1v[2]*kv[2] + q1v[3]*kv[3];
      }
      int kabs = k0 + kc;
      Sl[r0][kc] = (kabs <= q0 + r0) ? sc0 : -3e38f;
      Sl[r1][kc] = (kabs <= q0 + r1) ? sc1 : -3e38f;
      __syncthreads();
      if (tid < 32) {                       // online softmax per q-row
        float mo = mL[tid], mn = mo;
        #pragma unroll
        for (int c = 0; c < 16; ++c) mn = fmaxf(mn, Sl[tid][c]);
        float al = __expf(mo - mn);
        float sm = 0.f;
        #pragma unroll
        for (int c = 0; c < 16; ++c) {
          float p = __expf(Sl[tid][c] - mn);
          Sl[tid][c] = p; sm += p;
        }
        lL[tid] = lL[tid] * al + sm;
        mL[tid] = mn;
        aL[tid] = al;
      }
      __syncthreads();
      float a0 = aL[r0], a1 = aL[r1];
      #pragma unroll
      for (int c = 0; c < 16; ++c) { O0[c] *= a0; O1[c] *= a1; }
      #pragma unroll
      for (int k = 0; k < 16; ++k) {
        float p0 = Sl[r0][k], p1 = Sl[r1][k];
        #pragma unroll
        for (int c4 = 0; c4 < 4; ++c4) {
          f32x4 hh = *(const f32x4*)&Hs[k * 256 + hi * 16 + c4 * 4];
          O0[c4*4+0] += p0 * hh[0]; O0[c4*4+1] += p0 * hh[1];
          O0[c4*4+2] += p0 * hh[2]; O0[c4*4+3] += p0 * hh[3];
          O1[c4*4+0] += p1 * hh[0]; O1[c4*4+1] += p1 * hh[1];
          O1[c4*4+2] += p1 * hh[2]; O1[c4*4+3] += p1 * hh[3];
        }
      }
    }
    float li0 = 1.f / lL[r0], li1 = 1.f / lL[r1];
    float* d0 = &ctx[((size_t)b * SEQ + q0 + r0) * 256 + hi * 16];
    float* d1 = &ctx[((size_t)b * SEQ + q0 + r1) * 256 + hi * 16];
    #pragma unroll
    for (int c4 = 0; c4 < 4; ++c4) {
      f32x4 v0, v1;
      #pragma unroll
      for (int c = 0; c < 4; ++c) { v0[c] = O0[c4*4+c] * li0; v1[c] = O1[c4*4+c] * li1; }
      *(f32x4*)&d0[c4*4] = v0;
      *(f32x4*)&d1[c4*4] = v1;
    }
  }
}

extern "C" void kernel_launch(void* const* d_in, const int* in_sizes, int n_in,
                              void* d_out, int out_size, void* d_ws, size_t ws_size,
                              hipStream_t stream) {
  (void)in_sizes; (void)n_in; (void)out_size; (void)ws_size;
  const int*   x      = (const int*)  d_in[0];
  const float* emb    = (const float*)d_in[1];
  const float* w_ih   = (const float*)d_in[2];
  const float* w_hh   = (const float*)d_in[3];
  const float* b_ih   = (const float*)d_in[4];
  const float* b_hh   = (const float*)d_in[5];
  const float* attn_w = (const float*)d_in[6];
  const float* attn_b = (const float*)d_in[7];
  const float* comb_w = (const float*)d_in[8];
  const float* comb_b = (const float*)d_in[9];
  const float* fc_w   = (const float*)d_in[10];
  const float* fc_b   = (const float*)d_in[11];
  float* out = (float*)d_out;

  // workspace layout (floats): table | all_h | keys(->combined) | ctx
  float* ws    = (float*)d_ws;
  float* table = ws;                        // 100*768      =    76800
  float* all_h = table + 76800;             // 16384*256    =  4194304
  float* keys  = all_h + 4194304;           // 16384*256    =  4194304
  float* ctx   = keys  + 4194304;           // 16384*256    =  4194304
  float* hlast = out + (size_t)NB * SEQ * NV;

  build_table<<<100, 256, 0, stream>>>(emb, w_ih, b_ih, table);
  gru_scan<<<1, 1024, 0, stream>>>(x, w_hh, b_hh, table, all_h, hlast);
  // keys = all_h @ attn_w^T + attn_b
  gemm_bias<0><<<dim3(4, 128), 256, 0, stream>>>(all_h, 256, attn_w, attn_b, keys, 256, 256, 256);
  // ctx = softmax(causal(all_h @ keys^T)) @ all_h
  attention_kernel<<<dim3(32, 8), 256, 0, stream>>>(all_h, keys, ctx);
  // combined = tanh([all_h|ctx] @ comb_w^T + comb_b)  (into keys buffer)
  gemm_bias_cat<<<dim3(4, 128), 256, 0, stream>>>(all_h, ctx, comb_w, comb_b, keys);
  // out = combined @ fc_w^T + fc_b
  gemm_bias<0><<<dim3(2, 128), 256, 0, stream>>>(keys, 256, fc_w, fc_b, out, 100, 100, 256);
}

// Round 2
// 3020.072 us; speedup vs baseline: 1.3045x; 1.3045x over previous
//
#include <hip/hip_runtime.h>

#define SEQ  2048
#define NB   8
#define HD   256
#define G3   768
#define NV   100

typedef float f32x4 __attribute__((ext_vector_type(4)));
typedef int   i32x4 __attribute__((ext_vector_type(4)));

#define INV26 1.490116119384765625e-8f   // 2^-26

__device__ __forceinline__ float sigm(float x) {
  x = fminf(fmaxf(x, -30.f), 30.f);
  return 1.f / (1.f + __expf(-x));
}
__device__ __forceinline__ float tanh_fast(float x) {
  x = fminf(fmaxf(x, -15.f), 15.f);
  float e = __expf(2.f * x);
  return (e - 1.f) / (e + 1.f);
}

// ---------------- K1: xg lookup table, PACKED: table[(v*256+j)*4 + g] =
// emb[v]·w_ih[g*256+j] + b_ih[g*256+j]  (g = 0:r 1:z 2:n, [3] pad)
// -> gru_scan loads one dwordx4 per lane per step instead of 3 strided floats.
__global__ __launch_bounds__(256) void build_table(
    const float* __restrict__ emb, const float* __restrict__ w_ih,
    const float* __restrict__ b_ih, float* __restrict__ table) {
  __shared__ float eL[256];
  __shared__ float wL[256][37];
  int v = blockIdx.x, tid = threadIdx.x;
  eL[tid] = emb[v * HD + tid];
  for (int gt = 0; gt < 3; ++gt) {
    float acc = b_ih[gt * 256 + tid];
    for (int e0 = 0; e0 < HD; e0 += 32) {
      __syncthreads();
      #pragma unroll
      for (int i = 0; i < 32; ++i) {
        int idx = tid + i * 256;
        int r = idx >> 5, c = idx & 31;
        wL[r][c] = w_ih[(size_t)(gt * 256 + r) * HD + e0 + c];
      }
      __syncthreads();
      #pragma unroll
      for (int c = 0; c < 32; ++c) acc += eL[e0 + c] * wL[tid][c];
    }
    table[((size_t)v * 256 + tid) * 4 + gt] = acc;
  }
}

// ---------------- K2: GRU scan, one WG per batch (8 CUs), A-REPLICATED MFMA.
// Round-1 post-mortem: fusing 8 batches onto 1 CU made it VALU-bound (89%
// VALUBusy on the active CU). This keeps round-0's 8-CU parallelism but with
// round-1's "gates in-register" layout via M-dim replication:
//   A rows 2i = hi8 plane, rows 2i+1 = (lou-128) plane, i = 0..7 (8 copies).
//   C/D layout row = 4*quad+reg  ->  EVERY lane's acc regs (0,1) = (hi,lo).
// Wave wv holds weight rows {j, 256+j, 512+j} for its units j = wv*16+ncol,
// so each lane has r/z/n for its unit in-register after its 12 MFMAs: no hg
// LDS round-trip, no shfl, ONE barrier per step. hpk is 2 planes x 272 B
// (double-buffered); replication is done on the READ side (plane = ncol&1,
// an LDS broadcast - free). Verified i8 math (rounds 0/1, absmax 0.0039):
// q_w = round(w*2^11); hg = (256*D_hi + D_lo + 128*sum_k q_w)*2^-26 + b_hh.
__global__ void __launch_bounds__(1024) gru_scan(
    const int* __restrict__ x, const float* __restrict__ w_hh,
    const float* __restrict__ b_hh, const float* __restrict__ table,
    float* __restrict__ all_h, float* __restrict__ h_last) {
  __shared__ __align__(16) signed char hpk[2][2 * 272];  // [buf][plane*272]
  __shared__ int xs[SEQ];
  const int b = blockIdx.x;
  int tid = threadIdx.x;
  int lane = tid & 63, wv = tid >> 6;       // 16 waves
  int ncol = lane & 15, quad = lane >> 4;
  int j = wv * 16 + ncol;                   // this lane's hidden unit

  // stage token row + init buffer 0 for h=0 (hi plane = 0, lo plane = -128)
  for (int i = tid; i < SEQ; i += 1024) xs[i] = x[b * SEQ + i];
  if (tid < 2 * 272) hpk[0][tid] = (tid >= 272) ? (signed char)-128 : 0;

  // quantize weights into registers; wave wv owns rows j, 256+j, 512+j
  i32x4 bw[3][4];
  float Cn[3];
  #pragma unroll
  for (int t3 = 0; t3 < 3; ++t3) {
    int row = t3 * 256 + j;
    int sw = 0;
    #pragma unroll
    for (int c = 0; c < 4; ++c) {
      const float* p = w_hh + (size_t)row * HD + c * 64 + quad * 16;
      unsigned pw[4] = {0u, 0u, 0u, 0u};
      #pragma unroll
      for (int e = 0; e < 16; ++e) {
        int q = __float2int_rn(p[e] * 2048.f);       // w * 2^11
        q = max(-127, min(127, q));
        sw += q;
        pw[e >> 2] |= ((unsigned)(q & 255)) << ((e & 3) * 8);
      }
      bw[t3][c] = (i32x4){(int)pw[0], (int)pw[1], (int)pw[2], (int)pw[3]};
    }
    sw += __shfl_xor(sw, 16);
    sw += __shfl_xor(sw, 32);                        // full-K sum of q_w for row
    Cn[t3] = b_hh[row] + 128.f * (float)sw * INV26;
  }

  float hreg = 0.f;
  __syncthreads();                                   // xs + hpk[0] visible
  float xr, xz, xn;
  {
    int v = xs[0];
    f32x4 xg = *(const f32x4*)&table[((size_t)v * 256 + j) * 4];
    xr = xg[0]; xz = xg[1]; xn = xg[2];
  }
  int a_base = (ncol & 1) * 272 + quad * 16;         // plane by A-row parity

  for (int t = 0; t < SEQ; ++t) {
    const signed char* cb = hpk[t & 1];
    i32x4 a[4];
    #pragma unroll
    for (int c = 0; c < 4; ++c)
      a[c] = *(const i32x4*)&cb[a_base + c * 64];
    float hg[3];
    #pragma unroll
    for (int t3 = 0; t3 < 3; ++t3) {
      i32x4 acc = {0, 0, 0, 0};
      #pragma unroll
      for (int c = 0; c < 4; ++c)
        acc = __builtin_amdgcn_mfma_i32_16x16x64_i8(a[c], bw[t3][c], acc, 0, 0, 0);
      // acc reg r = D row 4*quad+r; rows even=hi, odd=lo in every quad
      hg[t3] = ((float)acc[0] * 256.f + (float)acc[1]) * INV26 + Cn[t3];
    }
    float r = sigm(xr + hg[0]);
    float z = sigm(xz + hg[1]);
    float n = tanh_fast(xn + r * hg[2]);
    float h = (1.f - z) * n + z * hreg;
    hreg = h;
    int q = min(__float2int_rn(h * 32768.f), 32767);
    int lou = q & 255;
    int hi8 = (q - lou) >> 8;
    signed char* nx = hpk[(t + 1) & 1];
    if (quad == 0) {                                 // 256 writer lanes
      nx[j] = (signed char)hi8;
      nx[272 + j] = (signed char)(lou - 128);
      all_h[((size_t)b * SEQ + t) * HD + j] = h;
    }
    int v = xs[(t + 1 < SEQ) ? t + 1 : t];           // prefetch next step's xg
    f32x4 xg = *(const f32x4*)&table[((size_t)v * 256 + j) * 4];
    xr = xg[0]; xz = xg[1]; xn = xg[2];
    __syncthreads();                                 // nx complete -> next step
  }
  if (quad == 0) h_last[b * HD + j] = hreg;
}

// ---------------- generic f32 GEMM  C[M,N] = A[M,K]·W[N,K]^T + bias
template<int ACT>
__global__ __launch_bounds__(256) void gemm_bias(
    const float* __restrict__ A, int lda,
    const float* __restrict__ W, const float* __restrict__ bias,
    float* __restrict__ C, int ldc, int N, int K) {
  __shared__ float As[128][36];
  __shared__ float Ws[64][36];
  int tid = threadIdx.x;
  int m0 = blockIdx.y * 128, n0 = blockIdx.x * 64;
  int ml = tid & 31, g = tid >> 5;
  float acc[4][8];
  #pragma unroll
  for (int i = 0; i < 4; ++i)
    #pragma unroll
    for (int jj = 0; jj < 8; ++jj) acc[i][jj] = 0.f;
  for (int k0 = 0; k0 < K; k0 += 32) {
    __syncthreads();
    #pragma unroll
    for (int i = 0; i < 4; ++i) {
      int idx = tid + i * 256;
      int r = idx >> 3, c4 = (idx & 7) * 4;
      *(f32x4*)&As[r][c4] = *(const f32x4*)&A[(size_t)(m0 + r) * lda + k0 + c4];
    }
    #pragma unroll
    for (int i = 0; i < 2; ++i) {
      int idx = tid + i * 256;
      int r = idx >> 3, c4 = (idx & 7) * 4;
      f32x4 wv = {0.f, 0.f, 0.f, 0.f};
      if (n0 + r < N) wv = *(const f32x4*)&W[(size_t)(n0 + r) * K + k0 + c4];
      *(f32x4*)&Ws[r][c4] = wv;
    }
    __syncthreads();
    #pragma unroll
    for (int k4 = 0; k4 < 32; k4 += 4) {
      f32x4 av[4], wv8[8];
      #pragma unroll
      for (int i = 0; i < 4; ++i) av[i] = *(const f32x4*)&As[ml + i * 32][k4];
      #pragma unroll
      for (int jj = 0; jj < 8; ++jj) wv8[jj] = *(const f32x4*)&Ws[g * 8 + jj][k4];
      #pragma unroll
      for (int kk = 0; kk < 4; ++kk)
        #pragma unroll
        for (int i = 0; i < 4; ++i)
          #pragma unroll
          for (int jj = 0; jj < 8; ++jj)
            acc[i][jj] += av[i][kk] * wv8[jj][kk];
    }
  }
  #pragma unroll
  for (int i = 0; i < 4; ++i) {
    int m = m0 + ml + i * 32;
    #pragma unroll
    for (int jj = 0; jj < 8; ++jj) {
      int n = n0 + g * 8 + jj;
      if (n < N) {
        float val = acc[i][jj] + bias[n];
        if (ACT) val = tanh_fast(val);
        C[(size_t)m * ldc + n] = val;
      }
    }
  }
}

// ---------------- comb GEMM: A = [all_h | ctx] split-K (K=512), tanh epilogue
__global__ __launch_bounds__(256) void gemm_bias_cat(
    const float* __restrict__ A1, const float* __restrict__ A2,
    const float* __restrict__ W, const float* __restrict__ bias,
    float* __restrict__ C) {
  __shared__ float As[128][36];
  __shared__ float Ws[64][36];
  const int K = 512;
  int tid = threadIdx.x;
  int m0 = blockIdx.y * 128, n0 = blockIdx.x * 64;
  int ml = tid & 31, g = tid >> 5;
  float acc[4][8];
  #pragma unroll
  for (int i = 0; i < 4; ++i)
    #pragma unroll
    for (int jj = 0; jj < 8; ++jj) acc[i][jj] = 0.f;
  for (int k0 = 0; k0 < K; k0 += 32) {
    const float* src = (k0 < 256) ? A1 : A2;
    int kb = (k0 < 256) ? k0 : k0 - 256;
    __syncthreads();
    #pragma unroll
    for (int i = 0; i < 4; ++i) {
      int idx = tid + i * 256;
      int r = idx >> 3, c4 = (idx & 7) * 4;
      *(f32x4*)&As[r][c4] = *(const f32x4*)&src[(size_t)(m0 + r) * 256 + kb + c4];
    }
    #pragma unroll
    for (int i = 0; i < 2; ++i) {
      int idx = tid + i * 256;
      int r = idx >> 3, c4 = (idx & 7) * 4;
      *(f32x4*)&Ws[r][c4] = *(const f32x4*)&W[(size_t)(n0 + r) * K + k0 + c4];
    }
    __syncthreads();
    #pragma unroll
    for (int k4 = 0; k4 < 32; k4 += 4) {
      f32x4 av[4], wv8[8];
      #pragma unroll
      for (int i = 0; i < 4; ++i) av[i] = *(const f32x4*)&As[ml + i * 32][k4];
      #pragma unroll
      for (int jj = 0; jj < 8; ++jj) wv8[jj] = *(const f32x4*)&Ws[g * 8 + jj][k4];
      #pragma unroll
      for (int kk = 0; kk < 4; ++kk)
        #pragma unroll
        for (int i = 0; i < 4; ++i)
          #pragma unroll
          for (int jj = 0; jj < 8; ++jj)
            acc[i][jj] += av[i][kk] * wv8[jj][kk];
    }
  }
  #pragma unroll
  for (int i = 0; i < 4; ++i) {
    int m = m0 + ml + i * 32;
    #pragma unroll
    for (int jj = 0; jj < 8; ++jj) {
      int n = n0 + g * 8 + jj;
      C[(size_t)m * 256 + n] = tanh_fast(acc[i][jj] + bias[n]);
    }
  }
}

// ---------------- K4: causal flash attention, q-tile 32 / k-tile 16, all f32.
// Qs/Ks XOR-swizzled -> conflict-free score loop.
__global__ __launch_bounds__(256) void attention_kernel(
    const float* __restrict__ all_h, const float* __restrict__ keys,
    float* __restrict__ ctx) {
  __shared__ float Qs[32 * 256];
  __shared__ float Ks[16 * 256];
  __shared__ float Hs[16 * 256];
  __shared__ float Sl[32][17];
  __shared__ float mL[32], lL[32], aL[32];
  int b = blockIdx.y, jb = blockIdx.x, tid = threadIdx.x;
  const float* hb = all_h + (size_t)b * SEQ * HD;
  const float* kb = keys  + (size_t)b * SEQ * HD;
  int qg = tid & 15, hi = tid >> 4;
  int r0 = qg * 2, r1 = r0 + 1;
  int sq = qg & 7;                          // Q swizzle bits for rows r0,r1
  for (int phase = 0; phase < 2; ++phase) {
    int qt = phase ? (63 - jb) : jb;
    int q0 = qt * 32;
    __syncthreads();
    #pragma unroll
    for (int i = 0; i < 8; ++i) {           // stage Q 32x256 (swizzled)
      int idx = tid + i * 256;
      int r = idx >> 6, cg = idx & 63;
      *(f32x4*)&Qs[r * 256 + ((cg ^ ((r >> 1) & 7)) << 2)] =
          *(const f32x4*)&hb[(size_t)(q0 + r) * HD + cg * 4];
    }
    if (tid < 32) { mL[tid] = -3e38f; lL[tid] = 0.f; }
    float O0[16], O1[16];
    #pragma unroll
    for (int c = 0; c < 16; ++c) { O0[c] = 0.f; O1[c] = 0.f; }
    int nkt = 2 * (qt + 1);
    for (int kt = 0; kt < nkt; ++kt) {
      int k0 = kt * 16;
      __syncthreads();
      #pragma unroll
      for (int i = 0; i < 4; ++i) {         // stage K (swizzled) + V, 16x256 each
        int idx = tid + i * 256;
        int r = idx >> 6, cg = idx & 63;
        *(f32x4*)&Ks[r * 256 + ((cg ^ (r & 7)) << 2)] =
            *(const f32x4*)&kb[(size_t)(k0 + r) * HD + cg * 4];
        *(f32x4*)&Hs[r * 256 + cg * 4] = *(const f32x4*)&hb[(size_t)(k0 + r) * HD + cg * 4];
      }
      __syncthreads();
      int kc = hi;
      int sk = kc & 7;
      float sc0 = 0.f, sc1 = 0.f;
      #pragma unroll 8
      for (int c = 0; c < 64; ++c) {
        f32x4 kv  = *(const f32x4*)&Ks[kc * 256 + ((c ^ sk) << 2)];
        f32x4 q0v = *(const f32x4*)&Qs[r0 * 256 + ((c ^ sq) << 2)];
        f32x4 q1v = *(const f32x4*)&Qs[r1 * 256 + ((c ^ sq) << 2)];
        sc0 += q0v[0]*kv[0] + q0v[1]*kv[1] + q0v[2]*kv[2] + q0v[3]*kv[3];
        sc1 += q1v[0]*kv[0] + q1v[1]*kv[1] + q1v[2]*kv[2] + q1v[3]*kv[3];
      }
      int kabs = k0 + kc;
      Sl[r0][kc] = (kabs <= q0 + r0) ? sc0 : -3e38f;
      Sl[r1][kc] = (kabs <= q0 + r1) ? sc1 : -3e38f;
      __syncthreads();
      if (tid < 32) {                       // online softmax per q-row
        float mo = mL[tid], mn = mo;
        #pragma unroll
        for (int c = 0; c < 16; ++c) mn = fmaxf(mn, Sl[tid][c]);
        float al = __expf(mo - mn);
        float sm = 0.f;
        #pragma unroll
        for (int c = 0; c < 16; ++c) {
          float p = __expf(Sl[tid][c] - mn);
          Sl[tid][c] = p; sm += p;
        }
        lL[tid] = lL[tid] * al + sm;
        mL[tid] = mn;
        aL[tid] = al;
      }
      __syncthreads();
      float a0 = aL[r0], a1 = aL[r1];
      #pragma unroll
      for (int c = 0; c < 16; ++c) { O0[c] *= a0; O1[c] *= a1; }
      #pragma unroll
      for (int k = 0; k < 16; ++k) {
        float p0 = Sl[r0][k], p1 = Sl[r1][k];
        #pragma unroll
        for (int c4 = 0; c4 < 4; ++c4) {
          f32x4 hh = *(const f32x4*)&Hs[k * 256 + hi * 16 + c4 * 4];
          O0[c4*4+0] += p0 * hh[0]; O0[c4*4+1] += p0 * hh[1];
          O0[c4*4+2] += p0 * hh[2]; O0[c4*4+3] += p0 * hh[3];
          O1[c4*4+0] += p1 * hh[0]; O1[c4*4+1] += p1 * hh[1];
          O1[c4*4+2] += p1 * hh[2]; O1[c4*4+3] += p1 * hh[3];
        }
      }
    }
    float li0 = 1.f / lL[r0], li1 = 1.f / lL[r1];
    float* d0 = &ctx[((size_t)b * SEQ + q0 + r0) * 256 + hi * 16];
    float* d1 = &ctx[((size_t)b * SEQ + q0 + r1) * 256 + hi * 16];
    #pragma unroll
    for (int c4 = 0; c4 < 4; ++c4) {
      f32x4 v0, v1;
      #pragma unroll
      for (int c = 0; c < 4; ++c) { v0[c] = O0[c4*4+c] * li0; v1[c] = O1[c4*4+c] * li1; }
      *(f32x4*)&d0[c4*4] = v0;
      *(f32x4*)&d1[c4*4] = v1;
    }
  }
}

extern "C" void kernel_launch(void* const* d_in, const int* in_sizes, int n_in,
                              void* d_out, int out_size, void* d_ws, size_t ws_size,
                              hipStream_t stream) {
  (void)in_sizes; (void)n_in; (void)out_size; (void)ws_size;
  const int*   x      = (const int*)  d_in[0];
  const float* emb    = (const float*)d_in[1];
  const float* w_ih   = (const float*)d_in[2];
  const float* w_hh   = (const float*)d_in[3];
  const float* b_ih   = (const float*)d_in[4];
  const float* b_hh   = (const float*)d_in[5];
  const float* attn_w = (const float*)d_in[6];
  const float* attn_b = (const float*)d_in[7];
  const float* comb_w = (const float*)d_in[8];
  const float* comb_b = (const float*)d_in[9];
  const float* fc_w   = (const float*)d_in[10];
  const float* fc_b   = (const float*)d_in[11];
  float* out = (float*)d_out;

  // workspace layout (floats): table(packed, 100*256*4) | all_h | keys | ctx
  float* ws    = (float*)d_ws;
  float* table = ws;                        // 100*256*4    =   102400
  float* all_h = table + 102400;            // 16384*256    =  4194304
  float* keys  = all_h + 4194304;           // 16384*256    =  4194304
  float* ctx   = keys  + 4194304;           // 16384*256    =  4194304
  float* hlast = out + (size_t)NB * SEQ * NV;

  build_table<<<100, 256, 0, stream>>>(emb, w_ih, b_ih, table);
  gru_scan<<<NB, 1024, 0, stream>>>(x, w_hh, b_hh, table, all_h, hlast);
  // keys = all_h @ attn_w^T + attn_b
  gemm_bias<0><<<dim3(4, 128), 256, 0, stream>>>(all_h, 256, attn_w, attn_b, keys, 256, 256, 256);
  // ctx = softmax(causal(all_h @ keys^T)) @ all_h
  attention_kernel<<<dim3(32, 8), 256, 0, stream>>>(all_h, keys, ctx);
  // combined = tanh([all_h|ctx] @ comb_w^T + comb_b)  (into keys buffer)
  gemm_bias_cat<<<dim3(4, 128), 256, 0, stream>>>(all_h, ctx, comb_w, comb_b, keys);
  // out = combined @ fc_w^T + fc_b
  gemm_bias<0><<<dim3(2, 128), 256, 0, stream>>>(keys, 256, fc_w, fc_b, out, 100, 100, 256);
}

// Round 3
// 2430.126 us; speedup vs baseline: 1.6211x; 1.2428x over previous
//
#include <hip/hip_runtime.h>

#define SEQ  2048
#define NB   8
#define HD   256
#define G3   768
#define NV   100

typedef float f32x4 __attribute__((ext_vector_type(4)));
typedef int   i32x4 __attribute__((ext_vector_type(4)));

#define INV26 1.490116119384765625e-8f   // 2^-26

__device__ __forceinline__ float rcp_fast(float x) {
  return __builtin_amdgcn_rcpf(x);       // v_rcp_f32, <=1 ulp: fine vs 2^-15 quant noise
}
__device__ __forceinline__ float sigm(float x) {
  x = fminf(fmaxf(x, -30.f), 30.f);
  return rcp_fast(1.f + __expf(-x));
}
__device__ __forceinline__ float tanh_fast(float x) {
  x = fminf(fmaxf(x, -15.f), 15.f);
  float e = __expf(2.f * x);
  return (e - 1.f) * rcp_fast(e + 1.f);
}

// ---------------- K1: xg lookup table, PACKED: table[(v*256+j)*4 + g] =
// emb[v]·w_ih[g*256+j] + b_ih[g*256+j]  (g = 0:r 1:z 2:n, [3] pad)
__global__ __launch_bounds__(256) void build_table(
    const float* __restrict__ emb, const float* __restrict__ w_ih,
    const float* __restrict__ b_ih, float* __restrict__ table) {
  __shared__ float eL[256];
  __shared__ float wL[256][37];
  int v = blockIdx.x, tid = threadIdx.x;
  eL[tid] = emb[v * HD + tid];
  for (int gt = 0; gt < 3; ++gt) {
    float acc = b_ih[gt * 256 + tid];
    for (int e0 = 0; e0 < HD; e0 += 32) {
      __syncthreads();
      #pragma unroll
      for (int i = 0; i < 32; ++i) {
        int idx = tid + i * 256;
        int r = idx >> 5, c = idx & 31;
        wL[r][c] = w_ih[(size_t)(gt * 256 + r) * HD + e0 + c];
      }
      __syncthreads();
      #pragma unroll
      for (int c = 0; c < 32; ++c) acc += eL[e0 + c] * wL[tid][c];
    }
    table[((size_t)v * 256 + tid) * 4 + gt] = acc;
  }
}

// ---------------- K2: GRU scan, one WG per batch (8 CUs), 8 waves.
// Round-2 post-mortem: A-replicated layout was VALU-issue-bound (73% of the
// active CUs) because all 4 quads computed identical gate math (4x redundant)
// and sigm/tanh used full-precision div sequences. This round:
//  - 8 waves x 2 unit-tiles/wave (units wv*32 + u*16 + ncol). Each lane runs
//    gate math for ONE unit, tile picked by quad&1 (6 cndmask on acc ints).
//    Redundancy 4x -> 2x AND waves/SIMD 4 -> 2: per-SIMD VALU issue ~halves.
//  - v_rcp_f32 for both activation divides.
// MFMA structure unchanged (192/step total, A-replicated planes, C/D regs
// (0,1) = (hi,lo) in every quad). One barrier/step, hpk double-buffered.
// Verified i8 math (rounds 0-2, absmax 0.0039): q_w = round(w*2^11);
// hg = (256*D_hi + D_lo + 128*sum_k q_w)*2^-26 + b_hh.
__global__ void __launch_bounds__(512) gru_scan(
    const int* __restrict__ x, const float* __restrict__ w_hh,
    const float* __restrict__ b_hh, const float* __restrict__ table,
    float* __restrict__ all_h, float* __restrict__ h_last) {
  __shared__ __align__(16) signed char hpk[2][2 * 272];  // [buf][plane*272]
  __shared__ int xs[SEQ];
  const int b = blockIdx.x;
  int tid = threadIdx.x;
  int lane = tid & 63, wv = tid >> 6;       // 8 waves
  int ncol = lane & 15, quad = lane >> 4;
  int usel = quad & 1;                      // which of the wave's 2 tiles
  int j = wv * 32 + usel * 16 + ncol;       // this lane's hidden unit

  // stage token row + init buffer 0 for h=0 (hi plane = 0, lo plane = -128)
  for (int i = tid; i < SEQ; i += 512) xs[i] = x[b * SEQ + i];
  for (int i = tid; i < 2 * 272; i += 512)
    hpk[0][i] = (i >= 272) ? (signed char)-128 : 0;

  // quantize weights into registers; wave wv owns unit rows wv*32 .. wv*32+31
  // (2 tiles x 3 gates x 4 K-chunks). All quads load all tiles (they hold
  // different K-slices); gate constants selected per-lane afterwards.
  i32x4 bw[2][3][4];
  float Cn2[2][3];
  #pragma unroll
  for (int u = 0; u < 2; ++u) {
    #pragma unroll
    for (int t3 = 0; t3 < 3; ++t3) {
      int row = t3 * 256 + wv * 32 + u * 16 + ncol;
      int sw = 0;
      #pragma unroll
      for (int c = 0; c < 4; ++c) {
        const float* p = w_hh + (size_t)row * HD + c * 64 + quad * 16;
        unsigned pw[4] = {0u, 0u, 0u, 0u};
        #pragma unroll
        for (int e = 0; e < 16; ++e) {
          int q = __float2int_rn(p[e] * 2048.f);     // w * 2^11
          q = max(-127, min(127, q));
          sw += q;
          pw[e >> 2] |= ((unsigned)(q & 255)) << ((e & 3) * 8);
        }
        bw[u][t3][c] = (i32x4){(int)pw[0], (int)pw[1], (int)pw[2], (int)pw[3]};
      }
      sw += __shfl_xor(sw, 16);
      sw += __shfl_xor(sw, 32);                      // full-K sum of q_w for row
      Cn2[u][t3] = b_hh[row] + 128.f * (float)sw * INV26;
    }
  }
  float Csel[3];
  #pragma unroll
  for (int t3 = 0; t3 < 3; ++t3) Csel[t3] = usel ? Cn2[1][t3] : Cn2[0][t3];

  float hreg = 0.f;
  __syncthreads();                                   // xs + hpk[0] visible
  float xr, xz, xn;
  {
    int v = xs[0];
    f32x4 xg = *(const f32x4*)&table[((size_t)v * 256 + j) * 4];
    xr = xg[0]; xz = xg[1]; xn = xg[2];
  }
  int a_base = (ncol & 1) * 272 + quad * 16;         // plane by A-row parity

  for (int t = 0; t < SEQ; ++t) {
    const signed char* cb = hpk[t & 1];
    i32x4 a[4];
    #pragma unroll
    for (int c = 0; c < 4; ++c)
      a[c] = *(const i32x4*)&cb[a_base + c * 64];
    float hg[3];
    #pragma unroll
    for (int t3 = 0; t3 < 3; ++t3) {
      i32x4 A0 = {0, 0, 0, 0}, A1 = {0, 0, 0, 0};
      #pragma unroll
      for (int c = 0; c < 4; ++c) {
        A0 = __builtin_amdgcn_mfma_i32_16x16x64_i8(a[c], bw[0][t3][c], A0, 0, 0, 0);
        A1 = __builtin_amdgcn_mfma_i32_16x16x64_i8(a[c], bw[1][t3][c], A1, 0, 0, 0);
      }
      // regs (0,1) = (hi,lo) planes in every quad; pick this lane's tile
      int d0 = usel ? A1[0] : A0[0];
      int d1 = usel ? A1[1] : A0[1];
      hg[t3] = ((float)d0 * 256.f + (float)d1) * INV26 + Csel[t3];
    }
    float r = sigm(xr + hg[0]);
    float z = sigm(xz + hg[1]);
    float n = tanh_fast(xn + r * hg[2]);
    float h = (1.f - z) * n + z * hreg;
    hreg = h;
    int q = min(__float2int_rn(h * 32768.f), 32767);
    int lou = q & 255;
    int hi8 = (q - lou) >> 8;
    signed char* nx = hpk[(t + 1) & 1];
    if (quad < 2) {                                  // one writer per unit
      nx[j] = (signed char)hi8;
      nx[272 + j] = (signed char)(lou - 128);
      all_h[((size_t)b * SEQ + t) * HD + j] = h;
    }
    int v = xs[(t + 1 < SEQ) ? t + 1 : t];           // prefetch next step's xg
    f32x4 xg = *(const f32x4*)&table[((size_t)v * 256 + j) * 4];
    xr = xg[0]; xz = xg[1]; xn = xg[2];
    __syncthreads();                                 // nx complete -> next step
  }
  if (quad < 2) h_last[b * HD + j] = hreg;
}

// ---------------- generic f32 GEMM  C[M,N] = A[M,K]·W[N,K]^T + bias
template<int ACT>
__global__ __launch_bounds__(256) void gemm_bias(
    const float* __restrict__ A, int lda,
    const float* __restrict__ W, const float* __restrict__ bias,
    float* __restrict__ C, int ldc, int N, int K) {
  __shared__ float As[128][36];
  __shared__ float Ws[64][36];
  int tid = threadIdx.x;
  int m0 = blockIdx.y * 128, n0 = blockIdx.x * 64;
  int ml = tid & 31, g = tid >> 5;
  float acc[4][8];
  #pragma unroll
  for (int i = 0; i < 4; ++i)
    #pragma unroll
    for (int jj = 0; jj < 8; ++jj) acc[i][jj] = 0.f;
  for (int k0 = 0; k0 < K; k0 += 32) {
    __syncthreads();
    #pragma unroll
    for (int i = 0; i < 4; ++i) {
      int idx = tid + i * 256;
      int r = idx >> 3, c4 = (idx & 7) * 4;
      *(f32x4*)&As[r][c4] = *(const f32x4*)&A[(size_t)(m0 + r) * lda + k0 + c4];
    }
    #pragma unroll
    for (int i = 0; i < 2; ++i) {
      int idx = tid + i * 256;
      int r = idx >> 3, c4 = (idx & 7) * 4;
      f32x4 wv = {0.f, 0.f, 0.f, 0.f};
      if (n0 + r < N) wv = *(const f32x4*)&W[(size_t)(n0 + r) * K + k0 + c4];
      *(f32x4*)&Ws[r][c4] = wv;
    }
    __syncthreads();
    #pragma unroll
    for (int k4 = 0; k4 < 32; k4 += 4) {
      f32x4 av[4], wv8[8];
      #pragma unroll
      for (int i = 0; i < 4; ++i) av[i] = *(const f32x4*)&As[ml + i * 32][k4];
      #pragma unroll
      for (int jj = 0; jj < 8; ++jj) wv8[jj] = *(const f32x4*)&Ws[g * 8 + jj][k4];
      #pragma unroll
      for (int kk = 0; kk < 4; ++kk)
        #pragma unroll
        for (int i = 0; i < 4; ++i)
          #pragma unroll
          for (int jj = 0; jj < 8; ++jj)
            acc[i][jj] += av[i][kk] * wv8[jj][kk];
    }
  }
  #pragma unroll
  for (int i = 0; i < 4; ++i) {
    int m = m0 + ml + i * 32;
    #pragma unroll
    for (int jj = 0; jj < 8; ++jj) {
      int n = n0 + g * 8 + jj;
      if (n < N) {
        float val = acc[i][jj] + bias[n];
        if (ACT) val = tanh_fast(val);
        C[(size_t)m * ldc + n] = val;
      }
    }
  }
}

// ---------------- comb GEMM: A = [all_h | ctx] split-K (K=512), tanh epilogue
__global__ __launch_bounds__(256) void gemm_bias_cat(
    const float* __restrict__ A1, const float* __restrict__ A2,
    const float* __restrict__ W, const float* __restrict__ bias,
    float* __restrict__ C) {
  __shared__ float As[128][36];
  __shared__ float Ws[64][36];
  const int K = 512;
  int tid = threadIdx.x;
  int m0 = blockIdx.y * 128, n0 = blockIdx.x * 64;
  int ml = tid & 31, g = tid >> 5;
  float acc[4][8];
  #pragma unroll
  for (int i = 0; i < 4; ++i)
    #pragma unroll
    for (int jj = 0; jj < 8; ++jj) acc[i][jj] = 0.f;
  for (int k0 = 0; k0 < K; k0 += 32) {
    const float* src = (k0 < 256) ? A1 : A2;
    int kb = (k0 < 256) ? k0 : k0 - 256;
    __syncthreads();
    #pragma unroll
    for (int i = 0; i < 4; ++i) {
      int idx = tid + i * 256;
      int r = idx >> 3, c4 = (idx & 7) * 4;
      *(f32x4*)&As[r][c4] = *(const f32x4*)&src[(size_t)(m0 + r) * 256 + kb + c4];
    }
    #pragma unroll
    for (int i = 0; i < 2; ++i) {
      int idx = tid + i * 256;
      int r = idx >> 3, c4 = (idx & 7) * 4;
      *(f32x4*)&Ws[r][c4] = *(const f32x4*)&W[(size_t)(n0 + r) * K + k0 + c4];
    }
    __syncthreads();
    #pragma unroll
    for (int k4 = 0; k4 < 32; k4 += 4) {
      f32x4 av[4], wv8[8];
      #pragma unroll
      for (int i = 0; i < 4; ++i) av[i] = *(const f32x4*)&As[ml + i * 32][k4];
      #pragma unroll
      for (int jj = 0; jj < 8; ++jj) wv8[jj] = *(const f32x4*)&Ws[g * 8 + jj][k4];
      #pragma unroll
      for (int kk = 0; kk < 4; ++kk)
        #pragma unroll
        for (int i = 0; i < 4; ++i)
          #pragma unroll
          for (int jj = 0; jj < 8; ++jj)
            acc[i][jj] += av[i][kk] * wv8[jj][kk];
    }
  }
  #pragma unroll
  for (int i = 0; i < 4; ++i) {
    int m = m0 + ml + i * 32;
    #pragma unroll
    for (int jj = 0; jj < 8; ++jj) {
      int n = n0 + g * 8 + jj;
      C[(size_t)m * 256 + n] = tanh_fast(acc[i][jj] + bias[n]);
    }
  }
}

// ---------------- K4: causal flash attention, q-tile 32 / k-tile 16, all f32.
// Qs/Ks XOR-swizzled -> conflict-free score loop.
__global__ __launch_bounds__(256) void attention_kernel(
    const float* __restrict__ all_h, const float* __restrict__ keys,
    float* __restrict__ ctx) {
  __shared__ float Qs[32 * 256];
  __shared__ float Ks[16 * 256];
  __shared__ float Hs[16 * 256];
  __shared__ float Sl[32][17];
  __shared__ float mL[32], lL[32], aL[32];
  int b = blockIdx.y, jb = blockIdx.x, tid = threadIdx.x;
  const float* hb = all_h + (size_t)b * SEQ * HD;
  const float* kb = keys  + (size_t)b * SEQ * HD;
  int qg = tid & 15, hi = tid >> 4;
  int r0 = qg * 2, r1 = r0 + 1;
  int sq = qg & 7;                          // Q swizzle bits for rows r0,r1
  for (int phase = 0; phase < 2; ++phase) {
    int qt = phase ? (63 - jb) : jb;
    int q0 = qt * 32;
    __syncthreads();
    #pragma unroll
    for (int i = 0; i < 8; ++i) {           // stage Q 32x256 (swizzled)
      int idx = tid + i * 256;
      int r = idx >> 6, cg = idx & 63;
      *(f32x4*)&Qs[r * 256 + ((cg ^ ((r >> 1) & 7)) << 2)] =
          *(const f32x4*)&hb[(size_t)(q0 + r) * HD + cg * 4];
    }
    if (tid < 32) { mL[tid] = -3e38f; lL[tid] = 0.f; }
    float O0[16], O1[16];
    #pragma unroll
    for (int c = 0; c < 16; ++c) { O0[c] = 0.f; O1[c] = 0.f; }
    int nkt = 2 * (qt + 1);
    for (int kt = 0; kt < nkt; ++kt) {
      int k0 = kt * 16;
      __syncthreads();
      #pragma unroll
      for (int i = 0; i < 4; ++i) {         // stage K (swizzled) + V, 16x256 each
        int idx = tid + i * 256;
        int r = idx >> 6, cg = idx & 63;
        *(f32x4*)&Ks[r * 256 + ((cg ^ (r & 7)) << 2)] =
            *(const f32x4*)&kb[(size_t)(k0 + r) * HD + cg * 4];
        *(f32x4*)&Hs[r * 256 + cg * 4] = *(const f32x4*)&hb[(size_t)(k0 + r) * HD + cg * 4];
      }
      __syncthreads();
      int kc = hi;
      int sk = kc & 7;
      float sc0 = 0.f, sc1 = 0.f;
      #pragma unroll 8
      for (int c = 0; c < 64; ++c) {
        f32x4 kv  = *(const f32x4*)&Ks[kc * 256 + ((c ^ sk) << 2)];
        f32x4 q0v = *(const f32x4*)&Qs[r0 * 256 + ((c ^ sq) << 2)];
        f32x4 q1v = *(const f32x4*)&Qs[r1 * 256 + ((c ^ sq) << 2)];
        sc0 += q0v[0]*kv[0] + q0v[1]*kv[1] + q0v[2]*kv[2] + q0v[3]*kv[3];
        sc1 += q1v[0]*kv[0] + q1v[1]*kv[1] + q1v[2]*kv[2] + q1v[3]*kv[3];
      }
      int kabs = k0 + kc;
      Sl[r0][kc] = (kabs <= q0 + r0) ? sc0 : -3e38f;
      Sl[r1][kc] = (kabs <= q0 + r1) ? sc1 : -3e38f;
      __syncthreads();
      if (tid < 32) {                       // online softmax per q-row
        float mo = mL[tid], mn = mo;
        #pragma unroll
        for (int c = 0; c < 16; ++c) mn = fmaxf(mn, Sl[tid][c]);
        float al = __expf(mo - mn);
        float sm = 0.f;
        #pragma unroll
        for (int c = 0; c < 16; ++c) {
          float p = __expf(Sl[tid][c] - mn);
          Sl[tid][c] = p; sm += p;
        }
        lL[tid] = lL[tid] * al + sm;
        mL[tid] = mn;
        aL[tid] = al;
      }
      __syncthreads();
      float a0 = aL[r0], a1 = aL[r1];
      #pragma unroll
      for (int c = 0; c < 16; ++c) { O0[c] *= a0; O1[c] *= a1; }
      #pragma unroll
      for (int k = 0; k < 16; ++k) {
        float p0 = Sl[r0][k], p1 = Sl[r1][k];
        #pragma unroll
        for (int c4 = 0; c4 < 4; ++c4) {
          f32x4 hh = *(const f32x4*)&Hs[k * 256 + hi * 16 + c4 * 4];
          O0[c4*4+0] += p0 * hh[0]; O0[c4*4+1] += p0 * hh[1];
          O0[c4*4+2] += p0 * hh[2]; O0[c4*4+3] += p0 * hh[3];
          O1[c4*4+0] += p1 * hh[0]; O1[c4*4+1] += p1 * hh[1];
          O1[c4*4+2] += p1 * hh[2]; O1[c4*4+3] += p1 * hh[3];
        }
      }
    }
    float li0 = 1.f / lL[r0], li1 = 1.f / lL[r1];
    float* d0 = &ctx[((size_t)b * SEQ + q0 + r0) * 256 + hi * 16];
    float* d1 = &ctx[((size_t)b * SEQ + q0 + r1) * 256 + hi * 16];
    #pragma unroll
    for (int c4 = 0; c4 < 4; ++c4) {
      f32x4 v0, v1;
      #pragma unroll
      for (int c = 0; c < 4; ++c) { v0[c] = O0[c4*4+c] * li0; v1[c] = O1[c4*4+c] * li1; }
      *(f32x4*)&d0[c4*4] = v0;
      *(f32x4*)&d1[c4*4] = v1;
    }
  }
}

extern "C" void kernel_launch(void* const* d_in, const int* in_sizes, int n_in,
                              void* d_out, int out_size, void* d_ws, size_t ws_size,
                              hipStream_t stream) {
  (void)in_sizes; (void)n_in; (void)out_size; (void)ws_size;
  const int*   x      = (const int*)  d_in[0];
  const float* emb    = (const float*)d_in[1];
  const float* w_ih   = (const float*)d_in[2];
  const float* w_hh   = (const float*)d_in[3];
  const float* b_ih   = (const float*)d_in[4];
  const float* b_hh   = (const float*)d_in[5];
  const float* attn_w = (const float*)d_in[6];
  const float* attn_b = (const float*)d_in[7];
  const float* comb_w = (const float*)d_in[8];
  const float* comb_b = (const float*)d_in[9];
  const float* fc_w   = (const float*)d_in[10];
  const float* fc_b   = (const float*)d_in[11];
  float* out = (float*)d_out;

  // workspace layout (floats): table(packed, 100*256*4) | all_h | keys | ctx
  float* ws    = (float*)d_ws;
  float* table = ws;                        // 100*256*4    =   102400
  float* all_h = table + 102400;            // 16384*256    =  4194304
  float* keys  = all_h + 4194304;           // 16384*256    =  4194304
  float* ctx   = keys  + 4194304;           // 16384*256    =  4194304
  float* hlast = out + (size_t)NB * SEQ * NV;

  build_table<<<100, 256, 0, stream>>>(emb, w_ih, b_ih, table);
  gru_scan<<<NB, 512, 0, stream>>>(x, w_hh, b_hh, table, all_h, hlast);
  // keys = all_h @ attn_w^T + attn_b
  gemm_bias<0><<<dim3(4, 128), 256, 0, stream>>>(all_h, 256, attn_w, attn_b, keys, 256, 256, 256);
  // ctx = softmax(causal(all_h @ keys^T)) @ all_h
  attention_kernel<<<dim3(32, 8), 256, 0, stream>>>(all_h, keys, ctx);
  // combined = tanh([all_h|ctx] @ comb_w^T + comb_b)  (into keys buffer)
  gemm_bias_cat<<<dim3(4, 128), 256, 0, stream>>>(all_h, ctx, comb_w, comb_b, keys);
  // out = combined @ fc_w^T + fc_b
  gemm_bias<0><<<dim3(2, 128), 256, 0, stream>>>(keys, 256, fc_w, fc_b, out, 100, 100, 256);
}

// Round 4
// 2378.554 us; speedup vs baseline: 1.6563x; 1.0217x over previous
//
#include <hip/hip_runtime.h>

#define SEQ  2048
#define NB   8
#define HD   256
#define G3   768
#define NV   100

typedef float f32x4 __attribute__((ext_vector_type(4)));
typedef int   i32x4 __attribute__((ext_vector_type(4)));

#define INV26 1.490116119384765625e-8f   // 2^-26

__device__ __forceinline__ float rcp_fast(float x) {
  return __builtin_amdgcn_rcpf(x);       // v_rcp_f32, <=1 ulp: fine vs 2^-15 quant noise
}
__device__ __forceinline__ float sigm(float x) {
  x = fminf(fmaxf(x, -30.f), 30.f);
  return rcp_fast(1.f + __expf(-x));
}
__device__ __forceinline__ float tanh_fast(float x) {
  x = fminf(fmaxf(x, -15.f), 15.f);
  float e = __expf(2.f * x);
  return (e - 1.f) * rcp_fast(e + 1.f);
}

// ---------------- K1: xg lookup table, PACKED: table[(v*256+j)*4 + g] =
// emb[v]·w_ih[g*256+j] + b_ih[g*256+j]  (g = 0:r 1:z 2:n, [3] pad)
__global__ __launch_bounds__(256) void build_table(
    const float* __restrict__ emb, const float* __restrict__ w_ih,
    const float* __restrict__ b_ih, float* __restrict__ table) {
  __shared__ float eL[256];
  __shared__ float wL[256][37];
  int v = blockIdx.x, tid = threadIdx.x;
  eL[tid] = emb[v * HD + tid];
  for (int gt = 0; gt < 3; ++gt) {
    float acc = b_ih[gt * 256 + tid];
    for (int e0 = 0; e0 < HD; e0 += 32) {
      __syncthreads();
      #pragma unroll
      for (int i = 0; i < 32; ++i) {
        int idx = tid + i * 256;
        int r = idx >> 5, c = idx & 31;
        wL[r][c] = w_ih[(size_t)(gt * 256 + r) * HD + e0 + c];
      }
      __syncthreads();
      #pragma unroll
      for (int c = 0; c < 32; ++c) acc += eL[e0 + c] * wL[tid][c];
    }
    table[((size_t)v * 256 + tid) * 4 + gt] = acc;
  }
}

// ---------------- K2: GRU scan, one WG per batch (8 CUs), 4 waves / 1 per SIMD.
// Round-3 post-mortem: VALU cost is per-WAVE-instruction; 2 waves/SIMD each
// issuing the ~100-instr gate stream = ~400 cyc/SIMD/step. This round: 4 waves
// x 4 unit-tiles/wave (unit j = wv*64 + quad*16 + ncol, tile picked by quad
// via STATIC cndmask selects over 4 named accumulators). Per-SIMD VALU issue
// halves again; per-SIMD MFMA unchanged (48/wave x ~5cyc = 240 cyc, 12
// independent 4-chains). Weights 192 VGPR/lane -> __launch_bounds__(256,1),
// ~250 VGPR, 1 wave/SIMD by design. xg prefetch hoisted to the top of the
// step so its ~300cyc global latency hides under the MFMA phase.
// MFMA math unchanged (verified rounds 0-3, absmax 0.0039): A rows 2i=hi8,
// 2i+1=lou-128 (8 copies); q_w = round(w*2^11);
// hg = (256*D_hi + D_lo + 128*sum_k q_w)*2^-26 + b_hh; C/D regs (0,1)=(hi,lo).
__global__ void __launch_bounds__(256, 1) gru_scan(
    const int* __restrict__ x, const float* __restrict__ w_hh,
    const float* __restrict__ b_hh, const float* __restrict__ table,
    float* __restrict__ all_h, float* __restrict__ h_last) {
  __shared__ __align__(16) signed char hpk[2][2 * 272];  // [buf][plane*272]
  __shared__ int xs[SEQ];
  const int b = blockIdx.x;
  int tid = threadIdx.x;
  int lane = tid & 63, wv = tid >> 6;       // 4 waves
  int ncol = lane & 15, quad = lane >> 4;
  int j = wv * 64 + quad * 16 + ncol;       // this lane's hidden unit (all 256)

  // stage token row + init buffer 0 for h=0 (hi plane = 0, lo plane = -128)
  for (int i = tid; i < SEQ; i += 256) xs[i] = x[b * SEQ + i];
  for (int i = tid; i < 2 * 272; i += 256)
    hpk[0][i] = (i >= 272) ? (signed char)-128 : 0;

  // quantize weights into registers; wave wv owns unit rows wv*64 .. wv*64+63
  // (4 tiles x 3 gates x 4 K-chunks = 192 VGPRs). Each quad holds a different
  // K-slice of every tile; gate constants selected per-lane afterwards.
  i32x4 bw[4][3][4];
  float Cn4[4][3];
  #pragma unroll
  for (int u = 0; u < 4; ++u) {
    #pragma unroll
    for (int t3 = 0; t3 < 3; ++t3) {
      int row = t3 * 256 + wv * 64 + u * 16 + ncol;
      int sw = 0;
      #pragma unroll
      for (int c = 0; c < 4; ++c) {
        const float* p = w_hh + (size_t)row * HD + c * 64 + quad * 16;
        unsigned pw[4] = {0u, 0u, 0u, 0u};
        #pragma unroll
        for (int e = 0; e < 16; ++e) {
          int q = __float2int_rn(p[e] * 2048.f);     // w * 2^11
          q = max(-127, min(127, q));
          sw += q;
          pw[e >> 2] |= ((unsigned)(q & 255)) << ((e & 3) * 8);
        }
        bw[u][t3][c] = (i32x4){(int)pw[0], (int)pw[1], (int)pw[2], (int)pw[3]};
      }
      sw += __shfl_xor(sw, 16);
      sw += __shfl_xor(sw, 32);                      // full-K sum of q_w for row
      Cn4[u][t3] = b_hh[row] + 128.f * (float)sw * INV26;
    }
  }
  // lane's tile = quad: static-index selects (no scratch)
  float Csel[3];
  #pragma unroll
  for (int t3 = 0; t3 < 3; ++t3) {
    float c0 = (quad & 1) ? Cn4[1][t3] : Cn4[0][t3];
    float c1 = (quad & 1) ? Cn4[3][t3] : Cn4[2][t3];
    Csel[t3] = (quad & 2) ? c1 : c0;
  }

  float hreg = 0.f;
  __syncthreads();                                   // xs + hpk[0] visible
  float xr, xz, xn;
  {
    int v = xs[0];
    f32x4 xg = *(const f32x4*)&table[((size_t)v * 256 + j) * 4];
    xr = xg[0]; xz = xg[1]; xn = xg[2];
  }
  int a_base = (ncol & 1) * 272 + quad * 16;         // plane by A-row parity

  for (int t = 0; t < SEQ; ++t) {
    const signed char* cb = hpk[t & 1];
    i32x4 a[4];
    #pragma unroll
    for (int c = 0; c < 4; ++c)
      a[c] = *(const i32x4*)&cb[a_base + c * 64];
    // hoisted prefetch: overlaps the MFMA phase
    int vnext = xs[(t + 1 < SEQ) ? t + 1 : t];
    f32x4 xgn = *(const f32x4*)&table[((size_t)vnext * 256 + j) * 4];
    float hg[3];
    #pragma unroll
    for (int t3 = 0; t3 < 3; ++t3) {
      i32x4 A0 = {0,0,0,0}, A1 = {0,0,0,0}, A2 = {0,0,0,0}, A3 = {0,0,0,0};
      #pragma unroll
      for (int c = 0; c < 4; ++c) {
        A0 = __builtin_amdgcn_mfma_i32_16x16x64_i8(a[c], bw[0][t3][c], A0, 0, 0, 0);
        A1 = __builtin_amdgcn_mfma_i32_16x16x64_i8(a[c], bw[1][t3][c], A1, 0, 0, 0);
        A2 = __builtin_amdgcn_mfma_i32_16x16x64_i8(a[c], bw[2][t3][c], A2, 0, 0, 0);
        A3 = __builtin_amdgcn_mfma_i32_16x16x64_i8(a[c], bw[3][t3][c], A3, 0, 0, 0);
      }
      // regs (0,1) = (hi,lo) planes in every quad; pick this lane's tile=quad
      int d0a = (quad & 1) ? A1[0] : A0[0];
      int d0b = (quad & 1) ? A3[0] : A2[0];
      int d1a = (quad & 1) ? A1[1] : A0[1];
      int d1b = (quad & 1) ? A3[1] : A2[1];
      int d0 = (quad & 2) ? d0b : d0a;
      int d1 = (quad & 2) ? d1b : d1a;
      hg[t3] = ((float)d0 * 256.f + (float)d1) * INV26 + Csel[t3];
    }
    float r = sigm(xr + hg[0]);
    float z = sigm(xz + hg[1]);
    float n = tanh_fast(xn + r * hg[2]);
    float h = (1.f - z) * n + z * hreg;
    hreg = h;
    int q = min(__float2int_rn(h * 32768.f), 32767);
    int lou = q & 255;
    int hi8 = (q - lou) >> 8;
    signed char* nx = hpk[(t + 1) & 1];
    nx[j] = (signed char)hi8;                        // every lane owns a unit
    nx[272 + j] = (signed char)(lou - 128);
    all_h[((size_t)b * SEQ + t) * HD + j] = h;
    xr = xgn[0]; xz = xgn[1]; xn = xgn[2];
    __syncthreads();                                 // nx complete -> next step
  }
  h_last[b * HD + j] = hreg;
}

// ---------------- generic f32 GEMM  C[M,N] = A[M,K]·W[N,K]^T + bias
template<int ACT>
__global__ __launch_bounds__(256) void gemm_bias(
    const float* __restrict__ A, int lda,
    const float* __restrict__ W, const float* __restrict__ bias,
    float* __restrict__ C, int ldc, int N, int K) {
  __shared__ float As[128][36];
  __shared__ float Ws[64][36];
  int tid = threadIdx.x;
  int m0 = blockIdx.y * 128, n0 = blockIdx.x * 64;
  int ml = tid & 31, g = tid >> 5;
  float acc[4][8];
  #pragma unroll
  for (int i = 0; i < 4; ++i)
    #pragma unroll
    for (int jj = 0; jj < 8; ++jj) acc[i][jj] = 0.f;
  for (int k0 = 0; k0 < K; k0 += 32) {
    __syncthreads();
    #pragma unroll
    for (int i = 0; i < 4; ++i) {
      int idx = tid + i * 256;
      int r = idx >> 3, c4 = (idx & 7) * 4;
      *(f32x4*)&As[r][c4] = *(const f32x4*)&A[(size_t)(m0 + r) * lda + k0 + c4];
    }
    #pragma unroll
    for (int i = 0; i < 2; ++i) {
      int idx = tid + i * 256;
      int r = idx >> 3, c4 = (idx & 7) * 4;
      f32x4 wv = {0.f, 0.f, 0.f, 0.f};
      if (n0 + r < N) wv = *(const f32x4*)&W[(size_t)(n0 + r) * K + k0 + c4];
      *(f32x4*)&Ws[r][c4] = wv;
    }
    __syncthreads();
    #pragma unroll
    for (int k4 = 0; k4 < 32; k4 += 4) {
      f32x4 av[4], wv8[8];
      #pragma unroll
      for (int i = 0; i < 4; ++i) av[i] = *(const f32x4*)&As[ml + i * 32][k4];
      #pragma unroll
      for (int jj = 0; jj < 8; ++jj) wv8[jj] = *(const f32x4*)&Ws[g * 8 + jj][k4];
      #pragma unroll
      for (int kk = 0; kk < 4; ++kk)
        #pragma unroll
        for (int i = 0; i < 4; ++i)
          #pragma unroll
          for (int jj = 0; jj < 8; ++jj)
            acc[i][jj] += av[i][kk] * wv8[jj][kk];
    }
  }
  #pragma unroll
  for (int i = 0; i < 4; ++i) {
    int m = m0 + ml + i * 32;
    #pragma unroll
    for (int jj = 0; jj < 8; ++jj) {
      int n = n0 + g * 8 + jj;
      if (n < N) {
        float val = acc[i][jj] + bias[n];
        if (ACT) val = tanh_fast(val);
        C[(size_t)m * ldc + n] = val;
      }
    }
  }
}

// ---------------- comb GEMM: A = [all_h | ctx] split-K (K=512), tanh epilogue
__global__ __launch_bounds__(256) void gemm_bias_cat(
    const float* __restrict__ A1, const float* __restrict__ A2,
    const float* __restrict__ W, const float* __restrict__ bias,
    float* __restrict__ C) {
  __shared__ float As[128][36];
  __shared__ float Ws[64][36];
  const int K = 512;
  int tid = threadIdx.x;
  int m0 = blockIdx.y * 128, n0 = blockIdx.x * 64;
  int ml = tid & 31, g = tid >> 5;
  float acc[4][8];
  #pragma unroll
  for (int i = 0; i < 4; ++i)
    #pragma unroll
    for (int jj = 0; jj < 8; ++jj) acc[i][jj] = 0.f;
  for (int k0 = 0; k0 < K; k0 += 32) {
    const float* src = (k0 < 256) ? A1 : A2;
    int kb = (k0 < 256) ? k0 : k0 - 256;
    __syncthreads();
    #pragma unroll
    for (int i = 0; i < 4; ++i) {
      int idx = tid + i * 256;
      int r = idx >> 3, c4 = (idx & 7) * 4;
      *(f32x4*)&As[r][c4] = *(const f32x4*)&src[(size_t)(m0 + r) * 256 + kb + c4];
    }
    #pragma unroll
    for (int i = 0; i < 2; ++i) {
      int idx = tid + i * 256;
      int r = idx >> 3, c4 = (idx & 7) * 4;
      *(f32x4*)&Ws[r][c4] = *(const f32x4*)&W[(size_t)(n0 + r) * K + k0 + c4];
    }
    __syncthreads();
    #pragma unroll
    for (int k4 = 0; k4 < 32; k4 += 4) {
      f32x4 av[4], wv8[8];
      #pragma unroll
      for (int i = 0; i < 4; ++i) av[i] = *(const f32x4*)&As[ml + i * 32][k4];
      #pragma unroll
      for (int jj = 0; jj < 8; ++jj) wv8[jj] = *(const f32x4*)&Ws[g * 8 + jj][k4];
      #pragma unroll
      for (int kk = 0; kk < 4; ++kk)
        #pragma unroll
        for (int i = 0; i < 4; ++i)
          #pragma unroll
          for (int jj = 0; jj < 8; ++jj)
            acc[i][jj] += av[i][kk] * wv8[jj][kk];
    }
  }
  #pragma unroll
  for (int i = 0; i < 4; ++i) {
    int m = m0 + ml + i * 32;
    #pragma unroll
    for (int jj = 0; jj < 8; ++jj) {
      int n = n0 + g * 8 + jj;
      C[(size_t)m * 256 + n] = tanh_fast(acc[i][jj] + bias[n]);
    }
  }
}

// ---------------- K4: causal flash attention, q-tile 32 / k-tile 16, all f32.
// Qs/Ks XOR-swizzled -> conflict-free score loop.
__global__ __launch_bounds__(256) void attention_kernel(
    const float* __restrict__ all_h, const float* __restrict__ keys,
    float* __restrict__ ctx) {
  __shared__ float Qs[32 * 256];
  __shared__ float Ks[16 * 256];
  __shared__ float Hs[16 * 256];
  __shared__ float Sl[32][17];
  __shared__ float mL[32], lL[32], aL[32];
  int b = blockIdx.y, jb = blockIdx.x, tid = threadIdx.x;
  const float* hb = all_h + (size_t)b * SEQ * HD;
  const float* kb = keys  + (size_t)b * SEQ * HD;
  int qg = tid & 15, hi = tid >> 4;
  int r0 = qg * 2, r1 = r0 + 1;
  int sq = qg & 7;                          // Q swizzle bits for rows r0,r1
  for (int phase = 0; phase < 2; ++phase) {
    int qt = phase ? (63 - jb) : jb;
    int q0 = qt * 32;
    __syncthreads();
    #pragma unroll
    for (int i = 0; i < 8; ++i) {           // stage Q 32x256 (swizzled)
      int idx = tid + i * 256;
      int r = idx >> 6, cg = idx & 63;
      *(f32x4*)&Qs[r * 256 + ((cg ^ ((r >> 1) & 7)) << 2)] =
          *(const f32x4*)&hb[(size_t)(q0 + r) * HD + cg * 4];
    }
    if (tid < 32) { mL[tid] = -3e38f; lL[tid] = 0.f; }
    float O0[16], O1[16];
    #pragma unroll
    for (int c = 0; c < 16; ++c) { O0[c] = 0.f; O1[c] = 0.f; }
    int nkt = 2 * (qt + 1);
    for (int kt = 0; kt < nkt; ++kt) {
      int k0 = kt * 16;
      __syncthreads();
      #pragma unroll
      for (int i = 0; i < 4; ++i) {         // stage K (swizzled) + V, 16x256 each
        int idx = tid + i * 256;
        int r = idx >> 6, cg = idx & 63;
        *(f32x4*)&Ks[r * 256 + ((cg ^ (r & 7)) << 2)] =
            *(const f32x4*)&kb[(size_t)(k0 + r) * HD + cg * 4];
        *(f32x4*)&Hs[r * 256 + cg * 4] = *(const f32x4*)&hb[(size_t)(k0 + r) * HD + cg * 4];
      }
      __syncthreads();
      int kc = hi;
      int sk = kc & 7;
      float sc0 = 0.f, sc1 = 0.f;
      #pragma unroll 8
      for (int c = 0; c < 64; ++c) {
        f32x4 kv  = *(const f32x4*)&Ks[kc * 256 + ((c ^ sk) << 2)];
        f32x4 q0v = *(const f32x4*)&Qs[r0 * 256 + ((c ^ sq) << 2)];
        f32x4 q1v = *(const f32x4*)&Qs[r1 * 256 + ((c ^ sq) << 2)];
        sc0 += q0v[0]*kv[0] + q0v[1]*kv[1] + q0v[2]*kv[2] + q0v[3]*kv[3];
        sc1 += q1v[0]*kv[0] + q1v[1]*kv[1] + q1v[2]*kv[2] + q1v[3]*kv[3];
      }
      int kabs = k0 + kc;
      Sl[r0][kc] = (kabs <= q0 + r0) ? sc0 : -3e38f;
      Sl[r1][kc] = (kabs <= q0 + r1) ? sc1 : -3e38f;
      __syncthreads();
      if (tid < 32) {                       // online softmax per q-row
        float mo = mL[tid], mn = mo;
        #pragma unroll
        for (int c = 0; c < 16; ++c) mn = fmaxf(mn, Sl[tid][c]);
        float al = __expf(mo - mn);
        float sm = 0.f;
        #pragma unroll
        for (int c = 0; c < 16; ++c) {
          float p = __expf(Sl[tid][c] - mn);
          Sl[tid][c] = p; sm += p;
        }
        lL[tid] = lL[tid] * al + sm;
        mL[tid] = mn;
        aL[tid] = al;
      }
      __syncthreads();
      float a0 = aL[r0], a1 = aL[r1];
      #pragma unroll
      for (int c = 0; c < 16; ++c) { O0[c] *= a0; O1[c] *= a1; }
      #pragma unroll
      for (int k = 0; k < 16; ++k) {
        float p0 = Sl[r0][k], p1 = Sl[r1][k];
        #pragma unroll
        for (int c4 = 0; c4 < 4; ++c4) {
          f32x4 hh = *(const f32x4*)&Hs[k * 256 + hi * 16 + c4 * 4];
          O0[c4*4+0] += p0 * hh[0]; O0[c4*4+1] += p0 * hh[1];
          O0[c4*4+2] += p0 * hh[2]; O0[c4*4+3] += p0 * hh[3];
          O1[c4*4+0] += p1 * hh[0]; O1[c4*4+1] += p1 * hh[1];
          O1[c4*4+2] += p1 * hh[2]; O1[c4*4+3] += p1 * hh[3];
        }
      }
    }
    float li0 = 1.f / lL[r0], li1 = 1.f / lL[r1];
    float* d0 = &ctx[((size_t)b * SEQ + q0 + r0) * 256 + hi * 16];
    float* d1 = &ctx[((size_t)b * SEQ + q0 + r1) * 256 + hi * 16];
    #pragma unroll
    for (int c4 = 0; c4 < 4; ++c4) {
      f32x4 v0, v1;
      #pragma unroll
      for (int c = 0; c < 4; ++c) { v0[c] = O0[c4*4+c] * li0; v1[c] = O1[c4*4+c] * li1; }
      *(f32x4*)&d0[c4*4] = v0;
      *(f32x4*)&d1[c4*4] = v1;
    }
  }
}

extern "C" void kernel_launch(void* const* d_in, const int* in_sizes, int n_in,
                              void* d_out, int out_size, void* d_ws, size_t ws_size,
                              hipStream_t stream) {
  (void)in_sizes; (void)n_in; (void)out_size; (void)ws_size;
  const int*   x      = (const int*)  d_in[0];
  const float* emb    = (const float*)d_in[1];
  const float* w_ih   = (const float*)d_in[2];
  const float* w_hh   = (const float*)d_in[3];
  const float* b_ih   = (const float*)d_in[4];
  const float* b_hh   = (const float*)d_in[5];
  const float* attn_w = (const float*)d_in[6];
  const float* attn_b = (const float*)d_in[7];
  const float* comb_w = (const float*)d_in[8];
  const float* comb_b = (const float*)d_in[9];
  const float* fc_w   = (const float*)d_in[10];
  const float* fc_b   = (const float*)d_in[11];
  float* out = (float*)d_out;

  // workspace layout (floats): table(packed, 100*256*4) | all_h | keys | ctx
  float* ws    = (float*)d_ws;
  float* table = ws;                        // 100*256*4    =   102400
  float* all_h = table + 102400;            // 16384*256    =  4194304
  float* keys  = all_h + 4194304;           // 16384*256    =  4194304
  float* ctx   = keys  + 4194304;           // 16384*256    =  4194304
  float* hlast = out + (size_t)NB * SEQ * NV;

  build_table<<<100, 256, 0, stream>>>(emb, w_ih, b_ih, table);
  gru_scan<<<NB, 256, 0, stream>>>(x, w_hh, b_hh, table, all_h, hlast);
  // keys = all_h @ attn_w^T + attn_b
  gemm_bias<0><<<dim3(4, 128), 256, 0, stream>>>(all_h, 256, attn_w, attn_b, keys, 256, 256, 256);
  // ctx = softmax(causal(all_h @ keys^T)) @ all_h
  attention_kernel<<<dim3(32, 8), 256, 0, stream>>>(all_h, keys, ctx);
  // combined = tanh([all_h|ctx] @ comb_w^T + comb_b)  (into keys buffer)
  gemm_bias_cat<<<dim3(4, 128), 256, 0, stream>>>(all_h, ctx, comb_w, comb_b, keys);
  // out = combined @ fc_w^T + fc_b
  gemm_bias<0><<<dim3(2, 128), 256, 0, stream>>>(keys, 256, fc_w, fc_b, out, 100, 100, 256);
}

// Round 5
// 2063.825 us; speedup vs baseline: 1.9089x; 1.1525x over previous
//
#include <hip/hip_runtime.h>

#define SEQ  2048
#define NB   8
#define HD   256
#define G3   768
#define NV   100

typedef float f32x4 __attribute__((ext_vector_type(4)));
typedef int   i32x4 __attribute__((ext_vector_type(4)));
typedef short s16x8 __attribute__((ext_vector_type(8)));
typedef unsigned short u16x4 __attribute__((ext_vector_type(4)));

#define INV26 1.490116119384765625e-8f   // 2^-26

__device__ __forceinline__ float rcp_fast(float x) {
  return __builtin_amdgcn_rcpf(x);       // v_rcp_f32, <=1 ulp: fine vs 2^-15 quant noise
}
__device__ __forceinline__ float sigm(float x) {
  x = fminf(fmaxf(x, -30.f), 30.f);
  return rcp_fast(1.f + __expf(-x));
}
__device__ __forceinline__ float tanh_fast(float x) {
  x = fminf(fmaxf(x, -15.f), 15.f);
  float e = __expf(2.f * x);
  return (e - 1.f) * rcp_fast(e + 1.f);
}
// split f32 into bf16 hi (truncate) + bf16 lo (truncated residual):
// f = hi + lo + eps, |eps| <= 2^-16 |f|
__device__ __forceinline__ void cvt_hilo(float f, unsigned short& h, unsigned short& l) {
  unsigned u = __float_as_uint(f);
  h = (unsigned short)(u >> 16);
  float r = f - __uint_as_float(u & 0xffff0000u);
  l = (unsigned short)(__float_as_uint(r) >> 16);
}

// ---------------- K1: xg lookup table, PACKED: table[(v*256+j)*4 + g] =
// emb[v]·w_ih[g*256+j] + b_ih[g*256+j]  (g = 0:r 1:z 2:n, [3] pad)
__global__ __launch_bounds__(256) void build_table(
    const float* __restrict__ emb, const float* __restrict__ w_ih,
    const float* __restrict__ b_ih, float* __restrict__ table) {
  __shared__ float eL[256];
  __shared__ float wL[256][37];
  int v = blockIdx.x, tid = threadIdx.x;
  eL[tid] = emb[v * HD + tid];
  for (int gt = 0; gt < 3; ++gt) {
    float acc = b_ih[gt * 256 + tid];
    for (int e0 = 0; e0 < HD; e0 += 32) {
      __syncthreads();
      #pragma unroll
      for (int i = 0; i < 32; ++i) {
        int idx = tid + i * 256;
        int r = idx >> 5, c = idx & 31;
        wL[r][c] = w_ih[(size_t)(gt * 256 + r) * HD + e0 + c];
      }
      __syncthreads();
      #pragma unroll
      for (int c = 0; c < 32; ++c) acc += eL[e0 + c] * wL[tid][c];
    }
    table[((size_t)v * 256 + tid) * 4 + gt] = acc;
  }
}

// ---------------- K2: GRU scan (round-3 version: 8 waves, 2 tiles/wave,
// VGPR 76 -> no spill; round-4's 4-wave/4-tile variant spilled the 192-reg
// weight array to scratch, VGPR_Count 136, and ran SLOWER: 1293 vs 1236 us).
// MFMA structure: A rows 2i=hi8, 2i+1=lou-128 (8 copies); q_w = round(w*2^11);
// hg = (256*D_hi + D_lo + 128*sum_k q_w)*2^-26 + b_hh; C/D regs (0,1)=(hi,lo).
__global__ void __launch_bounds__(512) gru_scan(
    const int* __restrict__ x, const float* __restrict__ w_hh,
    const float* __restrict__ b_hh, const float* __restrict__ table,
    float* __restrict__ all_h, float* __restrict__ h_last) {
  __shared__ __align__(16) signed char hpk[2][2 * 272];  // [buf][plane*272]
  __shared__ int xs[SEQ];
  const int b = blockIdx.x;
  int tid = threadIdx.x;
  int lane = tid & 63, wv = tid >> 6;       // 8 waves
  int ncol = lane & 15, quad = lane >> 4;
  int usel = quad & 1;                      // which of the wave's 2 tiles
  int j = wv * 32 + usel * 16 + ncol;       // this lane's hidden unit

  for (int i = tid; i < SEQ; i += 512) xs[i] = x[b * SEQ + i];
  for (int i = tid; i < 2 * 272; i += 512)
    hpk[0][i] = (i >= 272) ? (signed char)-128 : 0;

  i32x4 bw[2][3][4];
  float Cn2[2][3];
  #pragma unroll
  for (int u = 0; u < 2; ++u) {
    #pragma unroll
    for (int t3 = 0; t3 < 3; ++t3) {
      int row = t3 * 256 + wv * 32 + u * 16 + ncol;
      int sw = 0;
      #pragma unroll
      for (int c = 0; c < 4; ++c) {
        const float* p = w_hh + (size_t)row * HD + c * 64 + quad * 16;
        unsigned pw[4] = {0u, 0u, 0u, 0u};
        #pragma unroll
        for (int e = 0; e < 16; ++e) {
          int q = __float2int_rn(p[e] * 2048.f);     // w * 2^11
          q = max(-127, min(127, q));
          sw += q;
          pw[e >> 2] |= ((unsigned)(q & 255)) << ((e & 3) * 8);
        }
        bw[u][t3][c] = (i32x4){(int)pw[0], (int)pw[1], (int)pw[2], (int)pw[3]};
      }
      sw += __shfl_xor(sw, 16);
      sw += __shfl_xor(sw, 32);                      // full-K sum of q_w for row
      Cn2[u][t3] = b_hh[row] + 128.f * (float)sw * INV26;
    }
  }
  float Csel[3];
  #pragma unroll
  for (int t3 = 0; t3 < 3; ++t3) Csel[t3] = usel ? Cn2[1][t3] : Cn2[0][t3];

  float hreg = 0.f;
  __syncthreads();                                   // xs + hpk[0] visible
  float xr, xz, xn;
  {
    int v = xs[0];
    f32x4 xg = *(const f32x4*)&table[((size_t)v * 256 + j) * 4];
    xr = xg[0]; xz = xg[1]; xn = xg[2];
  }
  int a_base = (ncol & 1) * 272 + quad * 16;         // plane by A-row parity

  for (int t = 0; t < SEQ; ++t) {
    const signed char* cb = hpk[t & 1];
    i32x4 a[4];
    #pragma unroll
    for (int c = 0; c < 4; ++c)
      a[c] = *(const i32x4*)&cb[a_base + c * 64];
    float hg[3];
    #pragma unroll
    for (int t3 = 0; t3 < 3; ++t3) {
      i32x4 A0 = {0, 0, 0, 0}, A1 = {0, 0, 0, 0};
      #pragma unroll
      for (int c = 0; c < 4; ++c) {
        A0 = __builtin_amdgcn_mfma_i32_16x16x64_i8(a[c], bw[0][t3][c], A0, 0, 0, 0);
        A1 = __builtin_amdgcn_mfma_i32_16x16x64_i8(a[c], bw[1][t3][c], A1, 0, 0, 0);
      }
      int d0 = usel ? A1[0] : A0[0];
      int d1 = usel ? A1[1] : A0[1];
      hg[t3] = ((float)d0 * 256.f + (float)d1) * INV26 + Csel[t3];
    }
    float r = sigm(xr + hg[0]);
    float z = sigm(xz + hg[1]);
    float n = tanh_fast(xn + r * hg[2]);
    float h = (1.f - z) * n + z * hreg;
    hreg = h;
    int q = min(__float2int_rn(h * 32768.f), 32767);
    int lou = q & 255;
    int hi8 = (q - lou) >> 8;
    signed char* nx = hpk[(t + 1) & 1];
    if (quad < 2) {                                  // one writer per unit
      nx[j] = (signed char)hi8;
      nx[272 + j] = (signed char)(lou - 128);
      all_h[((size_t)b * SEQ + t) * HD + j] = h;
    }
    int v = xs[(t + 1 < SEQ) ? t + 1 : t];           // prefetch next step's xg
    f32x4 xg = *(const f32x4*)&table[((size_t)v * 256 + j) * 4];
    xr = xg[0]; xz = xg[1]; xn = xg[2];
    __syncthreads();                                 // nx complete -> next step
  }
  if (quad < 2) h_last[b * HD + j] = hreg;
}

// ---------------- generic f32 GEMM  C[M,N] = A[M,K]·W[N,K]^T + bias
template<int ACT>
__global__ __launch_bounds__(256) void gemm_bias(
    const float* __restrict__ A, int lda,
    const float* __restrict__ W, const float* __restrict__ bias,
    float* __restrict__ C, int ldc, int N, int K) {
  __shared__ float As[128][36];
  __shared__ float Ws[64][36];
  int tid = threadIdx.x;
  int m0 = blockIdx.y * 128, n0 = blockIdx.x * 64;
  int ml = tid & 31, g = tid >> 5;
  float acc[4][8];
  #pragma unroll
  for (int i = 0; i < 4; ++i)
    #pragma unroll
    for (int jj = 0; jj < 8; ++jj) acc[i][jj] = 0.f;
  for (int k0 = 0; k0 < K; k0 += 32) {
    __syncthreads();
    #pragma unroll
    for (int i = 0; i < 4; ++i) {
      int idx = tid + i * 256;
      int r = idx >> 3, c4 = (idx & 7) * 4;
      *(f32x4*)&As[r][c4] = *(const f32x4*)&A[(size_t)(m0 + r) * lda + k0 + c4];
    }
    #pragma unroll
    for (int i = 0; i < 2; ++i) {
      int idx = tid + i * 256;
      int r = idx >> 3, c4 = (idx & 7) * 4;
      f32x4 wv = {0.f, 0.f, 0.f, 0.f};
      if (n0 + r < N) wv = *(const f32x4*)&W[(size_t)(n0 + r) * K + k0 + c4];
      *(f32x4*)&Ws[r][c4] = wv;
    }
    __syncthreads();
    #pragma unroll
    for (int k4 = 0; k4 < 32; k4 += 4) {
      f32x4 av[4], wv8[8];
      #pragma unroll
      for (int i = 0; i < 4; ++i) av[i] = *(const f32x4*)&As[ml + i * 32][k4];
      #pragma unroll
      for (int jj = 0; jj < 8; ++jj) wv8[jj] = *(const f32x4*)&Ws[g * 8 + jj][k4];
      #pragma unroll
      for (int kk = 0; kk < 4; ++kk)
        #pragma unroll
        for (int i = 0; i < 4; ++i)
          #pragma unroll
          for (int jj = 0; jj < 8; ++jj)
            acc[i][jj] += av[i][kk] * wv8[jj][kk];
    }
  }
  #pragma unroll
  for (int i = 0; i < 4; ++i) {
    int m = m0 + ml + i * 32;
    #pragma unroll
    for (int jj = 0; jj < 8; ++jj) {
      int n = n0 + g * 8 + jj;
      if (n < N) {
        float val = acc[i][jj] + bias[n];
        if (ACT) val = tanh_fast(val);
        C[(size_t)m * ldc + n] = val;
      }
    }
  }
}

// ---------------- comb GEMM: A = [all_h | ctx] split-K (K=512), tanh epilogue
__global__ __launch_bounds__(256) void gemm_bias_cat(
    const float* __restrict__ A1, const float* __restrict__ A2,
    const float* __restrict__ W, const float* __restrict__ bias,
    float* __restrict__ C) {
  __shared__ float As[128][36];
  __shared__ float Ws[64][36];
  const int K = 512;
  int tid = threadIdx.x;
  int m0 = blockIdx.y * 128, n0 = blockIdx.x * 64;
  int ml = tid & 31, g = tid >> 5;
  float acc[4][8];
  #pragma unroll
  for (int i = 0; i < 4; ++i)
    #pragma unroll
    for (int jj = 0; jj < 8; ++jj) acc[i][jj] = 0.f;
  for (int k0 = 0; k0 < K; k0 += 32) {
    const float* src = (k0 < 256) ? A1 : A2;
    int kb = (k0 < 256) ? k0 : k0 - 256;
    __syncthreads();
    #pragma unroll
    for (int i = 0; i < 4; ++i) {
      int idx = tid + i * 256;
      int r = idx >> 3, c4 = (idx & 7) * 4;
      *(f32x4*)&As[r][c4] = *(const f32x4*)&src[(size_t)(m0 + r) * 256 + kb + c4];
    }
    #pragma unroll
    for (int i = 0; i < 2; ++i) {
      int idx = tid + i * 256;
      int r = idx >> 3, c4 = (idx & 7) * 4;
      *(f32x4*)&Ws[r][c4] = *(const f32x4*)&W[(size_t)(n0 + r) * K + k0 + c4];
    }
    __syncthreads();
    #pragma unroll
    for (int k4 = 0; k4 < 32; k4 += 4) {
      f32x4 av[4], wv8[8];
      #pragma unroll
      for (int i = 0; i < 4; ++i) av[i] = *(const f32x4*)&As[ml + i * 32][k4];
      #pragma unroll
      for (int jj = 0; jj < 8; ++jj) wv8[jj] = *(const f32x4*)&Ws[g * 8 + jj][k4];
      #pragma unroll
      for (int kk = 0; kk < 4; ++kk)
        #pragma unroll
        for (int i = 0; i < 4; ++i)
          #pragma unroll
          for (int jj = 0; jj < 8; ++jj)
            acc[i][jj] += av[i][kk] * wv8[jj][kk];
    }
  }
  #pragma unroll
  for (int i = 0; i < 4; ++i) {
    int m = m0 + ml + i * 32;
    #pragma unroll
    for (int jj = 0; jj < 8; ++jj) {
      int n = n0 + g * 8 + jj;
      C[(size_t)m * 256 + n] = tanh_fast(acc[i][jj] + bias[n]);
    }
  }
}

// ---------------- K4: causal flash attention on bf16 MFMA (bf16x3 split).
// Q-block 64 rows (4 waves x 16), K-tile 16 keys. Per kt:
//   S = Qhi·Khi + Qlo·Khi + Qhi·Klo  (3 passes x 8 d-chunks, f32 acc)
//   online softmax in-register (row = key dim lives in lane&15 -> shfl_xor)
//   P -> bf16 hi/lo via per-wave LDS transpose (D-layout -> A-layout, no bar)
//   ctx += Phi·Vhi + Phi·Vlo + Plo·Vhi  (V^T staged in LDS, keys 16..31 = 0)
// Frag conventions (same as verified gru i8 code): A/B lane k = (l>>4)*8+e
// contiguous; C/D col=l&15, row=(l>>4)*4+reg. Dropped lo·lo terms ~2^-16 rel.
// Masked lanes force p=0 explicitly (NOT just -3e38 scores: a fully-masked
// tile would give exp(s-m)=exp(0)=1 otherwise).
// LDS pads: K rows 264 (2-way), V^T rows 24 (2-way), P rows 24; all 16B-aligned.
__global__ __launch_bounds__(256, 1) void attention_kernel(
    const float* __restrict__ all_h, const float* __restrict__ keys,
    float* __restrict__ ctxg) {
  __shared__ __align__(16) unsigned short Khi[16][264], Klo[16][264];
  __shared__ __align__(16) unsigned short Vhi[256][24], Vlo[256][24];
  __shared__ __align__(16) unsigned short Pb[4][2][16][24];
  const int b = blockIdx.y, qb = blockIdx.x;
  int tid = threadIdx.x, lane = tid & 63, wv = tid >> 6;
  int lm = lane & 15, kg = lane >> 4;
  const float* hb = all_h + (size_t)b * SEQ * HD;
  const float* kb = keys  + (size_t)b * SEQ * HD;
  const int q0 = qb * 64 + wv * 16;        // wave's 16 q-rows

  // Q fragments (hi/lo), lane holds Q[q0+lm][ch*32 + kg*8 + e]
  s16x8 Qh[8], Ql[8];
  {
    const float* qp = hb + (size_t)(q0 + lm) * HD;
    #pragma unroll
    for (int ch = 0; ch < 8; ++ch) {
      union { s16x8 v; unsigned short u[8]; } uh, ul;
      f32x4 a0 = *(const f32x4*)&qp[ch * 32 + kg * 8];
      f32x4 a1 = *(const f32x4*)&qp[ch * 32 + kg * 8 + 4];
      #pragma unroll
      for (int e = 0; e < 4; ++e) {
        cvt_hilo(a0[e], uh.u[e], ul.u[e]);
        cvt_hilo(a1[e], uh.u[4 + e], ul.u[4 + e]);
      }
      Qh[ch] = uh.v; Ql[ch] = ul.v;
    }
  }

  f32x4 co[16];
  #pragma unroll
  for (int ht = 0; ht < 16; ++ht) co[ht] = (f32x4){0.f, 0.f, 0.f, 0.f};
  float mo[4] = {-3e38f, -3e38f, -3e38f, -3e38f};
  float lr[4] = {0.f, 0.f, 0.f, 0.f};

  const int nkt = 4 * qb + 4;
  for (int kt = 0; kt < nkt; ++kt) {
    int k0 = kt * 16;
    __syncthreads();                       // prev tile consumed
    #pragma unroll
    for (int i = 0; i < 4; ++i) {          // stage K + V^T (16 keys x 256 d)
      int idx = tid + i * 256;
      int r = idx & 15, cg = idx >> 4;     // key row, d-group (0..63)
      f32x4 kv = *(const f32x4*)&kb[(size_t)(k0 + r) * HD + cg * 4];
      f32x4 vv = *(const f32x4*)&hb[(size_t)(k0 + r) * HD + cg * 4];
      u16x4 khv, klv;
      #pragma unroll
      for (int e = 0; e < 4; ++e) {
        unsigned short h16, l16;
        cvt_hilo(kv[e], h16, l16);
        khv[e] = h16; klv[e] = l16;
      }
      *(u16x4*)&Khi[r][cg * 4] = khv;
      *(u16x4*)&Klo[r][cg * 4] = klv;
      #pragma unroll
      for (int e = 0; e < 4; ++e) {
        unsigned short h16, l16;
        cvt_hilo(vv[e], h16, l16);
        Vhi[cg * 4 + e][r] = h16;
        Vlo[cg * 4 + e][r] = l16;
      }
    }
    __syncthreads();                       // tile ready

    // ---- QK^T (16q x 16key), 6 accs to break dependency chains
    f32x4 acc[6];
    #pragma unroll
    for (int i = 0; i < 6; ++i) acc[i] = (f32x4){0.f, 0.f, 0.f, 0.f};
    #pragma unroll
    for (int ch = 0; ch < 8; ++ch) {
      s16x8 bh = *(const s16x8*)&Khi[lm][ch * 32 + kg * 8];
      s16x8 bl = *(const s16x8*)&Klo[lm][ch * 32 + kg * 8];
      int a = (ch & 1) * 3;
      acc[a + 0] = __builtin_amdgcn_mfma_f32_16x16x32_bf16(Qh[ch], bh, acc[a + 0], 0, 0, 0);
      acc[a + 1] = __builtin_amdgcn_mfma_f32_16x16x32_bf16(Ql[ch], bh, acc[a + 1], 0, 0, 0);
      acc[a + 2] = __builtin_amdgcn_mfma_f32_16x16x32_bf16(Qh[ch], bl, acc[a + 2], 0, 0, 0);
    }
    // ---- online softmax (q-row = kg*4+r, key = lm)
    float p[4], al[4];
    #pragma unroll
    for (int r = 0; r < 4; ++r) {
      float s = acc[0][r] + acc[1][r] + acc[2][r] + acc[3][r] + acc[4][r] + acc[5][r];
      int valid = (k0 + lm) <= (q0 + kg * 4 + r);
      float t = valid ? s : -3e38f;
      t = fmaxf(t, __shfl_xor(t, 1));
      t = fmaxf(t, __shfl_xor(t, 2));
      t = fmaxf(t, __shfl_xor(t, 4));
      t = fmaxf(t, __shfl_xor(t, 8));
      float mn = fmaxf(mo[r], t);
      al[r] = __expf(mo[r] - mn);
      float pv = valid ? __expf(s - mn) : 0.f;
      p[r] = pv;
      float rs = pv;
      rs += __shfl_xor(rs, 1);
      rs += __shfl_xor(rs, 2);
      rs += __shfl_xor(rs, 4);
      rs += __shfl_xor(rs, 8);
      lr[r] = lr[r] * al[r] + rs;
      mo[r] = mn;
    }
    // ---- P transpose D->A via per-wave LDS (wave-internal, no barrier)
    #pragma unroll
    for (int r = 0; r < 4; ++r) {
      unsigned short ph, pl;
      cvt_hilo(p[r], ph, pl);
      Pb[wv][0][kg * 4 + r][lm] = ph;
      Pb[wv][1][kg * 4 + r][lm] = pl;
    }
    s16x8 pah = {0, 0, 0, 0, 0, 0, 0, 0}, pal = {0, 0, 0, 0, 0, 0, 0, 0};
    if (kg < 2) {                          // keys 16..31 of the A-frag are zero
      pah = *(const s16x8*)&Pb[wv][0][lm][kg * 8];
      pal = *(const s16x8*)&Pb[wv][1][lm][kg * 8];
    }
    // ---- rescale ctx, then PV accumulate
    #pragma unroll
    for (int ht = 0; ht < 16; ++ht) {
      f32x4 c = co[ht];
      #pragma unroll
      for (int r = 0; r < 4; ++r) c[r] *= al[r];
      s16x8 vh = {0, 0, 0, 0, 0, 0, 0, 0}, vl = {0, 0, 0, 0, 0, 0, 0, 0};
      if (kg < 2) {
        vh = *(const s16x8*)&Vhi[ht * 16 + lm][kg * 8];
        vl = *(const s16x8*)&Vlo[ht * 16 + lm][kg * 8];
      }
      c = __builtin_amdgcn_mfma_f32_16x16x32_bf16(pah, vh, c, 0, 0, 0);
      c = __builtin_amdgcn_mfma_f32_16x16x32_bf16(pah, vl, c, 0, 0, 0);
      c = __builtin_amdgcn_mfma_f32_16x16x32_bf16(pal, vh, c, 0, 0, 0);
      co[ht] = c;
    }
  }
  float li[4];
  #pragma unroll
  for (int r = 0; r < 4; ++r) li[r] = rcp_fast(lr[r]);
  #pragma unroll
  for (int ht = 0; ht < 16; ++ht)
    #pragma unroll
    for (int r = 0; r < 4; ++r)
      ctxg[((size_t)b * SEQ + q0 + kg * 4 + r) * HD + ht * 16 + lm] = co[ht][r] * li[r];
}

extern "C" void kernel_launch(void* const* d_in, const int* in_sizes, int n_in,
                              void* d_out, int out_size, void* d_ws, size_t ws_size,
                              hipStream_t stream) {
  (void)in_sizes; (void)n_in; (void)out_size; (void)ws_size;
  const int*   x      = (const int*)  d_in[0];
  const float* emb    = (const float*)d_in[1];
  const float* w_ih   = (const float*)d_in[2];
  const float* w_hh   = (const float*)d_in[3];
  const float* b_ih   = (const float*)d_in[4];
  const float* b_hh   = (const float*)d_in[5];
  const float* attn_w = (const float*)d_in[6];
  const float* attn_b = (const float*)d_in[7];
  const float* comb_w = (const float*)d_in[8];
  const float* comb_b = (const float*)d_in[9];
  const float* fc_w   = (const float*)d_in[10];
  const float* fc_b   = (const float*)d_in[11];
  float* out = (float*)d_out;

  // workspace layout (floats): table(packed, 100*256*4) | all_h | keys | ctx
  float* ws    = (float*)d_ws;
  float* table = ws;                        // 100*256*4    =   102400
  float* all_h = table + 102400;            // 16384*256    =  4194304
  float* keys  = all_h + 4194304;           // 16384*256    =  4194304
  float* ctx   = keys  + 4194304;           // 16384*256    =  4194304
  float* hlast = out + (size_t)NB * SEQ * NV;

  build_table<<<100, 256, 0, stream>>>(emb, w_ih, b_ih, table);
  gru_scan<<<NB, 512, 0, stream>>>(x, w_hh, b_hh, table, all_h, hlast);
  // keys = all_h @ attn_w^T + attn_b
  gemm_bias<0><<<dim3(4, 128), 256, 0, stream>>>(all_h, 256, attn_w, attn_b, keys, 256, 256, 256);
  // ctx = softmax(causal(all_h @ keys^T)) @ all_h   (bf16x3 MFMA flash attn)
  attention_kernel<<<dim3(32, 8), 256, 0, stream>>>(all_h, keys, ctx);
  // combined = tanh([all_h|ctx] @ comb_w^T + comb_b)  (into keys buffer)
  gemm_bias_cat<<<dim3(4, 128), 256, 0, stream>>>(all_h, ctx, comb_w, comb_b, keys);
  // out = combined @ fc_w^T + fc_b
  gemm_bias<0><<<dim3(2, 128), 256, 0, stream>>>(keys, 256, fc_w, fc_b, out, 100, 100, 256);
}

// Round 6
// 1954.444 us; speedup vs baseline: 2.0157x; 1.0560x over previous
//
#include <hip/hip_runtime.h>

#define SEQ  2048
#define NB   8
#define HD   256
#define G3   768
#define NV   100
#define KVB  32

typedef float f32x4 __attribute__((ext_vector_type(4)));
typedef int   i32x4 __attribute__((ext_vector_type(4)));
typedef short s16x8 __attribute__((ext_vector_type(8)));
typedef unsigned short u16x4 __attribute__((ext_vector_type(4)));

#define INV26 1.490116119384765625e-8f   // 2^-26

__device__ __forceinline__ float rcp_fast(float x) {
  return __builtin_amdgcn_rcpf(x);       // v_rcp_f32, <=1 ulp: fine vs 2^-15 quant noise
}
__device__ __forceinline__ float sigm(float x) {
  x = fminf(fmaxf(x, -30.f), 30.f);
  return rcp_fast(1.f + __expf(-x));
}
__device__ __forceinline__ float tanh_fast(float x) {
  x = fminf(fmaxf(x, -15.f), 15.f);
  float e = __expf(2.f * x);
  return (e - 1.f) * rcp_fast(e + 1.f);
}
// split f32 into bf16 hi (truncate) + bf16 lo (truncated residual)
__device__ __forceinline__ void cvt_hilo(float f, unsigned short& h, unsigned short& l) {
  unsigned u = __float_as_uint(f);
  h = (unsigned short)(u >> 16);
  float r = f - __uint_as_float(u & 0xffff0000u);
  l = (unsigned short)(__float_as_uint(r) >> 16);
}

// ---------------- K1: xg lookup table, PACKED: table[(v*256+j)*4 + g]
__global__ __launch_bounds__(256) void build_table(
    const float* __restrict__ emb, const float* __restrict__ w_ih,
    const float* __restrict__ b_ih, float* __restrict__ table) {
  __shared__ float eL[256];
  __shared__ float wL[256][37];
  int v = blockIdx.x, tid = threadIdx.x;
  eL[tid] = emb[v * HD + tid];
  for (int gt = 0; gt < 3; ++gt) {
    float acc = b_ih[gt * 256 + tid];
    for (int e0 = 0; e0 < HD; e0 += 32) {
      __syncthreads();
      #pragma unroll
      for (int i = 0; i < 32; ++i) {
        int idx = tid + i * 256;
        int r = idx >> 5, c = idx & 31;
        wL[r][c] = w_ih[(size_t)(gt * 256 + r) * HD + e0 + c];
      }
      __syncthreads();
      #pragma unroll
      for (int c = 0; c < 32; ++c) acc += eL[e0 + c] * wL[tid][c];
    }
    table[((size_t)v * 256 + tid) * 4 + gt] = acc;
  }
}

// ---------------- K2: GRU scan (round-3 version, near its structural floor:
// 48 i8-MFMA/SIMD/step ~ 980cyc issue vs 1450 measured). VGPR 76, no spill.
__global__ void __launch_bounds__(512) gru_scan(
    const int* __restrict__ x, const float* __restrict__ w_hh,
    const float* __restrict__ b_hh, const float* __restrict__ table,
    float* __restrict__ all_h, float* __restrict__ h_last) {
  __shared__ __align__(16) signed char hpk[2][2 * 272];  // [buf][plane*272]
  __shared__ int xs[SEQ];
  const int b = blockIdx.x;
  int tid = threadIdx.x;
  int lane = tid & 63, wv = tid >> 6;       // 8 waves
  int ncol = lane & 15, quad = lane >> 4;
  int usel = quad & 1;                      // which of the wave's 2 tiles
  int j = wv * 32 + usel * 16 + ncol;       // this lane's hidden unit

  for (int i = tid; i < SEQ; i += 512) xs[i] = x[b * SEQ + i];
  for (int i = tid; i < 2 * 272; i += 512)
    hpk[0][i] = (i >= 272) ? (signed char)-128 : 0;

  i32x4 bw[2][3][4];
  float Cn2[2][3];
  #pragma unroll
  for (int u = 0; u < 2; ++u) {
    #pragma unroll
    for (int t3 = 0; t3 < 3; ++t3) {
      int row = t3 * 256 + wv * 32 + u * 16 + ncol;
      int sw = 0;
      #pragma unroll
      for (int c = 0; c < 4; ++c) {
        const float* p = w_hh + (size_t)row * HD + c * 64 + quad * 16;
        unsigned pw[4] = {0u, 0u, 0u, 0u};
        #pragma unroll
        for (int e = 0; e < 16; ++e) {
          int q = __float2int_rn(p[e] * 2048.f);     // w * 2^11
          q = max(-127, min(127, q));
          sw += q;
          pw[e >> 2] |= ((unsigned)(q & 255)) << ((e & 3) * 8);
        }
        bw[u][t3][c] = (i32x4){(int)pw[0], (int)pw[1], (int)pw[2], (int)pw[3]};
      }
      sw += __shfl_xor(sw, 16);
      sw += __shfl_xor(sw, 32);
      Cn2[u][t3] = b_hh[row] + 128.f * (float)sw * INV26;
    }
  }
  float Csel[3];
  #pragma unroll
  for (int t3 = 0; t3 < 3; ++t3) Csel[t3] = usel ? Cn2[1][t3] : Cn2[0][t3];

  float hreg = 0.f;
  __syncthreads();
  float xr, xz, xn;
  {
    int v = xs[0];
    f32x4 xg = *(const f32x4*)&table[((size_t)v * 256 + j) * 4];
    xr = xg[0]; xz = xg[1]; xn = xg[2];
  }
  int a_base = (ncol & 1) * 272 + quad * 16;

  for (int t = 0; t < SEQ; ++t) {
    const signed char* cb = hpk[t & 1];
    i32x4 a[4];
    #pragma unroll
    for (int c = 0; c < 4; ++c)
      a[c] = *(const i32x4*)&cb[a_base + c * 64];
    float hg[3];
    #pragma unroll
    for (int t3 = 0; t3 < 3; ++t3) {
      i32x4 A0 = {0, 0, 0, 0}, A1 = {0, 0, 0, 0};
      #pragma unroll
      for (int c = 0; c < 4; ++c) {
        A0 = __builtin_amdgcn_mfma_i32_16x16x64_i8(a[c], bw[0][t3][c], A0, 0, 0, 0);
        A1 = __builtin_amdgcn_mfma_i32_16x16x64_i8(a[c], bw[1][t3][c], A1, 0, 0, 0);
      }
      int d0 = usel ? A1[0] : A0[0];
      int d1 = usel ? A1[1] : A0[1];
      hg[t3] = ((float)d0 * 256.f + (float)d1) * INV26 + Csel[t3];
    }
    float r = sigm(xr + hg[0]);
    float z = sigm(xz + hg[1]);
    float n = tanh_fast(xn + r * hg[2]);
    float h = (1.f - z) * n + z * hreg;
    hreg = h;
    int q = min(__float2int_rn(h * 32768.f), 32767);
    int lou = q & 255;
    int hi8 = (q - lou) >> 8;
    signed char* nx = hpk[(t + 1) & 1];
    if (quad < 2) {
      nx[j] = (signed char)hi8;
      nx[272 + j] = (signed char)(lou - 128);
      all_h[((size_t)b * SEQ + t) * HD + j] = h;
    }
    int v = xs[(t + 1 < SEQ) ? t + 1 : t];
    f32x4 xg = *(const f32x4*)&table[((size_t)v * 256 + j) * 4];
    xr = xg[0]; xz = xg[1]; xn = xg[2];
    __syncthreads();
  }
  if (quad < 2) h_last[b * HD + j] = hreg;
}

// ---------------- generic f32 GEMM  C[M,N] = A[M,K]·W[N,K]^T + bias
template<int ACT>
__global__ __launch_bounds__(256) void gemm_bias(
    const float* __restrict__ A, int lda,
    const float* __restrict__ W, const float* __restrict__ bias,
    float* __restrict__ C, int ldc, int N, int K) {
  __shared__ float As[128][36];
  __shared__ float Ws[64][36];
  int tid = threadIdx.x;
  int m0 = blockIdx.y * 128, n0 = blockIdx.x * 64;
  int ml = tid & 31, g = tid >> 5;
  float acc[4][8];
  #pragma unroll
  for (int i = 0; i < 4; ++i)
    #pragma unroll
    for (int jj = 0; jj < 8; ++jj) acc[i][jj] = 0.f;
  for (int k0 = 0; k0 < K; k0 += 32) {
    __syncthreads();
    #pragma unroll
    for (int i = 0; i < 4; ++i) {
      int idx = tid + i * 256;
      int r = idx >> 3, c4 = (idx & 7) * 4;
      *(f32x4*)&As[r][c4] = *(const f32x4*)&A[(size_t)(m0 + r) * lda + k0 + c4];
    }
    #pragma unroll
    for (int i = 0; i < 2; ++i) {
      int idx = tid + i * 256;
      int r = idx >> 3, c4 = (idx & 7) * 4;
      f32x4 wv = {0.f, 0.f, 0.f, 0.f};
      if (n0 + r < N) wv = *(const f32x4*)&W[(size_t)(n0 + r) * K + k0 + c4];
      *(f32x4*)&Ws[r][c4] = wv;
    }
    __syncthreads();
    #pragma unroll
    for (int k4 = 0; k4 < 32; k4 += 4) {
      f32x4 av[4], wv8[8];
      #pragma unroll
      for (int i = 0; i < 4; ++i) av[i] = *(const f32x4*)&As[ml + i * 32][k4];
      #pragma unroll
      for (int jj = 0; jj < 8; ++jj) wv8[jj] = *(const f32x4*)&Ws[g * 8 + jj][k4];
      #pragma unroll
      for (int kk = 0; kk < 4; ++kk)
        #pragma unroll
        for (int i = 0; i < 4; ++i)
          #pragma unroll
          for (int jj = 0; jj < 8; ++jj)
            acc[i][jj] += av[i][kk] * wv8[jj][kk];
    }
  }
  #pragma unroll
  for (int i = 0; i < 4; ++i) {
    int m = m0 + ml + i * 32;
    #pragma unroll
    for (int jj = 0; jj < 8; ++jj) {
      int n = n0 + g * 8 + jj;
      if (n < N) {
        float val = acc[i][jj] + bias[n];
        if (ACT) val = tanh_fast(val);
        C[(size_t)m * ldc + n] = val;
      }
    }
  }
}

// ---------------- comb GEMM: A = [all_h | ctx] split-K (K=512), tanh epilogue
__global__ __launch_bounds__(256) void gemm_bias_cat(
    const float* __restrict__ A1, const float* __restrict__ A2,
    const float* __restrict__ W, const float* __restrict__ bias,
    float* __restrict__ C) {
  __shared__ float As[128][36];
  __shared__ float Ws[64][36];
  const int K = 512;
  int tid = threadIdx.x;
  int m0 = blockIdx.y * 128, n0 = blockIdx.x * 64;
  int ml = tid & 31, g = tid >> 5;
  float acc[4][8];
  #pragma unroll
  for (int i = 0; i < 4; ++i)
    #pragma unroll
    for (int jj = 0; jj < 8; ++jj) acc[i][jj] = 0.f;
  for (int k0 = 0; k0 < K; k0 += 32) {
    const float* src = (k0 < 256) ? A1 : A2;
    int kb = (k0 < 256) ? k0 : k0 - 256;
    __syncthreads();
    #pragma unroll
    for (int i = 0; i < 4; ++i) {
      int idx = tid + i * 256;
      int r = idx >> 3, c4 = (idx & 7) * 4;
      *(f32x4*)&As[r][c4] = *(const f32x4*)&src[(size_t)(m0 + r) * 256 + kb + c4];
    }
    #pragma unroll
    for (int i = 0; i < 2; ++i) {
      int idx = tid + i * 256;
      int r = idx >> 3, c4 = (idx & 7) * 4;
      *(f32x4*)&Ws[r][c4] = *(const f32x4*)&W[(size_t)(n0 + r) * K + k0 + c4];
    }
    __syncthreads();
    #pragma unroll
    for (int k4 = 0; k4 < 32; k4 += 4) {
      f32x4 av[4], wv8[8];
      #pragma unroll
      for (int i = 0; i < 4; ++i) av[i] = *(const f32x4*)&As[ml + i * 32][k4];
      #pragma unroll
      for (int jj = 0; jj < 8; ++jj) wv8[jj] = *(const f32x4*)&Ws[g * 8 + jj][k4];
      #pragma unroll
      for (int kk = 0; kk < 4; ++kk)
        #pragma unroll
        for (int i = 0; i < 4; ++i)
          #pragma unroll
          for (int jj = 0; jj < 8; ++jj)
            acc[i][jj] += av[i][kk] * wv8[jj][kk];
    }
  }
  #pragma unroll
  for (int i = 0; i < 4; ++i) {
    int m = m0 + ml + i * 32;
    #pragma unroll
    for (int jj = 0; jj < 8; ++jj) {
      int n = n0 + g * 8 + jj;
      C[(size_t)m * 256 + n] = tanh_fast(acc[i][jj] + bias[n]);
    }
  }
}

// ---------------- K4: causal flash attention, bf16x3 MFMA, KVB=32 tiles.
// Round-5 post-mortem fixes (attn was ~670us, 4-5x model):
//  (1) d-major staging -> fully coalesced global reads (was 16 lanes @ 1KB
//      stride = 16 cache lines/quarter-wave).
//  (2) lane-contiguous LDS layouts: reader lane L reads [block][L*16B] ->
//      conflict-free ds_read_b128 by construction (was 8-way on K: row
//      stride 132 dw = bank 4*(lm+kg)). Blocks padded +8B (516 hw) so the
//      power-of-2 block strides don't collapse staging writes onto 2 banks.
//  (3) KVB=32: full-width PV A-frags (was half zeros) -> 48 PV MFMA covers
//      32 keys not 16; softmax shfl/rescale/barriers amortized 2x per key.
// Numerics identical to round 5 (bf16 hi/lo x3 terms, p=0 on masked lanes).
__global__ __launch_bounds__(256, 1) void attention_kernel(
    const float* __restrict__ all_h, const float* __restrict__ keys,
    float* __restrict__ ctxg) {
  // K element (key, d): [grp=key>>4][ch=d>>5][(kg=(d&31)>>3)*16 + key&15][e=d&7]
  __shared__ __align__(16) unsigned short KH[2][8][516], KL[2][8][516];
  // V element (key, d): [ht=d>>4][(kg=key>>3)*16 + d&15][e=key&7]
  __shared__ __align__(16) unsigned short VH[16][516], VL[16][516];
  // P element (qrow, key): [wv][hi/lo][(key>>3)*16 + qrow][key&7]
  __shared__ __align__(16) unsigned short PB[4][2][520];
  const int b = blockIdx.y, qb = blockIdx.x;
  int tid = threadIdx.x, lane = tid & 63, wv = tid >> 6;
  int lm = lane & 15, kg = lane >> 4;
  const float* hb = all_h + (size_t)b * SEQ * HD;
  const float* kb = keys  + (size_t)b * SEQ * HD;
  const int q0 = qb * 64 + wv * 16;        // wave's 16 q-rows

  // Q fragments (hi/lo): lane holds Q[q0+lm][ch*32 + kg*8 + e]
  s16x8 Qh[8], Ql[8];
  {
    const float* qp = hb + (size_t)(q0 + lm) * HD;
    #pragma unroll
    for (int ch = 0; ch < 8; ++ch) {
      union { s16x8 v; unsigned short u[8]; } uh, ul;
      f32x4 a0 = *(const f32x4*)&qp[ch * 32 + kg * 8];
      f32x4 a1 = *(const f32x4*)&qp[ch * 32 + kg * 8 + 4];
      #pragma unroll
      for (int e = 0; e < 4; ++e) {
        cvt_hilo(a0[e], uh.u[e], ul.u[e]);
        cvt_hilo(a1[e], uh.u[4 + e], ul.u[4 + e]);
      }
      Qh[ch] = uh.v; Ql[ch] = ul.v;
    }
  }

  f32x4 co[16];
  #pragma unroll
  for (int ht = 0; ht < 16; ++ht) co[ht] = (f32x4){0.f, 0.f, 0.f, 0.f};
  float mo[4] = {-3e38f, -3e38f, -3e38f, -3e38f};
  float lr[4] = {0.f, 0.f, 0.f, 0.f};

  const int nkt = 2 * qb + 2;
  for (int kt = 0; kt < nkt; ++kt) {
    int k0 = kt * KVB;
    __syncthreads();                       // prev tile consumed
    #pragma unroll
    for (int i = 0; i < 8; ++i) {          // d-major staging: 32 keys x 256 d
      int idx = tid + i * 256;
      int r = idx >> 6, c = idx & 63;      // key row, d-group (f32x4)
      f32x4 kv = *(const f32x4*)&kb[(size_t)(k0 + r) * HD + c * 4];
      f32x4 vv = *(const f32x4*)&hb[(size_t)(k0 + r) * HD + c * 4];
      u16x4 khv, klv;
      #pragma unroll
      for (int e = 0; e < 4; ++e) {
        unsigned short h16, l16;
        cvt_hilo(kv[e], h16, l16);
        khv[e] = h16; klv[e] = l16;
      }
      int ch = c >> 3, kgs = (c & 7) >> 1;
      int off = (kgs * 16 + (r & 15)) * 8 + (c & 1) * 4;
      *(u16x4*)&KH[r >> 4][ch][off] = khv;
      *(u16x4*)&KL[r >> 4][ch][off] = klv;
      int kgv = r >> 3, ev = r & 7, ht = c >> 2;
      #pragma unroll
      for (int e = 0; e < 4; ++e) {
        unsigned short h16, l16;
        cvt_hilo(vv[e], h16, l16);
        int o = (kgv * 16 + (c & 3) * 4 + e) * 8 + ev;
        VH[ht][o] = h16; VL[ht][o] = l16;
      }
    }
    __syncthreads();                       // tile ready

    // ---- QK^T: two 16-key groups, 3 hi/lo terms each
    float s[4][2];
    #pragma unroll
    for (int g = 0; g < 2; ++g) {
      f32x4 a0 = {0.f,0.f,0.f,0.f}, a1 = {0.f,0.f,0.f,0.f}, a2 = {0.f,0.f,0.f,0.f};
      #pragma unroll
      for (int ch = 0; ch < 8; ++ch) {
        s16x8 bh = *(const s16x8*)&KH[g][ch][lane * 8];
        s16x8 bl = *(const s16x8*)&KL[g][ch][lane * 8];
        a0 = __builtin_amdgcn_mfma_f32_16x16x32_bf16(Qh[ch], bh, a0, 0, 0, 0);
        a1 = __builtin_amdgcn_mfma_f32_16x16x32_bf16(Ql[ch], bh, a1, 0, 0, 0);
        a2 = __builtin_amdgcn_mfma_f32_16x16x32_bf16(Qh[ch], bl, a2, 0, 0, 0);
      }
      #pragma unroll
      for (int r = 0; r < 4; ++r) s[r][g] = a0[r] + a1[r] + a2[r];
    }
    // ---- online softmax (q-row = kg*4+r; keys lm and 16+lm)
    float p[4][2], al[4];
    #pragma unroll
    for (int r = 0; r < 4; ++r) {
      int qrow = q0 + kg * 4 + r;
      int va = (k0 + lm) <= qrow, vb = (k0 + 16 + lm) <= qrow;
      float ta = va ? s[r][0] : -3e38f;
      float tb = vb ? s[r][1] : -3e38f;
      float t = fmaxf(ta, tb);
      t = fmaxf(t, __shfl_xor(t, 1));
      t = fmaxf(t, __shfl_xor(t, 2));
      t = fmaxf(t, __shfl_xor(t, 4));
      t = fmaxf(t, __shfl_xor(t, 8));
      float mn = fmaxf(mo[r], t);
      al[r] = __expf(mo[r] - mn);
      float pa = va ? __expf(s[r][0] - mn) : 0.f;
      float pb = vb ? __expf(s[r][1] - mn) : 0.f;
      p[r][0] = pa; p[r][1] = pb;
      float rs = pa + pb;
      rs += __shfl_xor(rs, 1);
      rs += __shfl_xor(rs, 2);
      rs += __shfl_xor(rs, 4);
      rs += __shfl_xor(rs, 8);
      lr[r] = lr[r] * al[r] + rs;
      mo[r] = mn;
    }
    // ---- P -> A-frag layout via per-wave LDS (wave-internal, no barrier)
    #pragma unroll
    for (int r = 0; r < 4; ++r)
      #pragma unroll
      for (int g = 0; g < 2; ++g) {
        unsigned short ph, pl;
        cvt_hilo(p[r][g], ph, pl);
        int key = g * 16 + lm;
        int o = ((key >> 3) * 16 + kg * 4 + r) * 8 + (key & 7);
        PB[wv][0][o] = ph;
        PB[wv][1][o] = pl;
      }
    s16x8 pah = *(const s16x8*)&PB[wv][0][lane * 8];
    s16x8 pal = *(const s16x8*)&PB[wv][1][lane * 8];
    // ---- rescale + PV (full 32-key K-dim per MFMA)
    #pragma unroll
    for (int ht = 0; ht < 16; ++ht) {
      f32x4 c = co[ht];
      #pragma unroll
      for (int r = 0; r < 4; ++r) c[r] *= al[r];
      s16x8 vh = *(const s16x8*)&VH[ht][lane * 8];
      s16x8 vl = *(const s16x8*)&VL[ht][lane * 8];
      c = __builtin_amdgcn_mfma_f32_16x16x32_bf16(pah, vh, c, 0, 0, 0);
      c = __builtin_amdgcn_mfma_f32_16x16x32_bf16(pah, vl, c, 0, 0, 0);
      c = __builtin_amdgcn_mfma_f32_16x16x32_bf16(pal, vh, c, 0, 0, 0);
      co[ht] = c;
    }
  }
  float li[4];
  #pragma unroll
  for (int r = 0; r < 4; ++r) li[r] = rcp_fast(lr[r]);
  #pragma unroll
  for (int ht = 0; ht < 16; ++ht)
    #pragma unroll
    for (int r = 0; r < 4; ++r)
      ctxg[((size_t)b * SEQ + q0 + kg * 4 + r) * HD + ht * 16 + lm] = co[ht][r] * li[r];
}

extern "C" void kernel_launch(void* const* d_in, const int* in_sizes, int n_in,
                              void* d_out, int out_size, void* d_ws, size_t ws_size,
                              hipStream_t stream) {
  (void)in_sizes; (void)n_in; (void)out_size; (void)ws_size;
  const int*   x      = (const int*)  d_in[0];
  const float* emb    = (const float*)d_in[1];
  const float* w_ih   = (const float*)d_in[2];
  const float* w_hh   = (const float*)d_in[3];
  const float* b_ih   = (const float*)d_in[4];
  const float* b_hh   = (const float*)d_in[5];
  const float* attn_w = (const float*)d_in[6];
  const float* attn_b = (const float*)d_in[7];
  const float* comb_w = (const float*)d_in[8];
  const float* comb_b = (const float*)d_in[9];
  const float* fc_w   = (const float*)d_in[10];
  const float* fc_b   = (const float*)d_in[11];
  float* out = (float*)d_out;

  // workspace layout (floats): table(packed, 100*256*4) | all_h | keys | ctx
  float* ws    = (float*)d_ws;
  float* table = ws;                        // 100*256*4    =   102400
  float* all_h = table + 102400;            // 16384*256    =  4194304
  float* keys  = all_h + 4194304;           // 16384*256    =  4194304
  float* ctx   = keys  + 4194304;           // 16384*256    =  4194304
  float* hlast = out + (size_t)NB * SEQ * NV;

  build_table<<<100, 256, 0, stream>>>(emb, w_ih, b_ih, table);
  gru_scan<<<NB, 512, 0, stream>>>(x, w_hh, b_hh, table, all_h, hlast);
  // keys = all_h @ attn_w^T + attn_b
  gemm_bias<0><<<dim3(4, 128), 256, 0, stream>>>(all_h, 256, attn_w, attn_b, keys, 256, 256, 256);
  // ctx = softmax(causal(all_h @ keys^T)) @ all_h   (bf16x3 MFMA flash attn)
  attention_kernel<<<dim3(32, 8), 256, 0, stream>>>(all_h, keys, ctx);
  // combined = tanh([all_h|ctx] @ comb_w^T + comb_b)  (into keys buffer)
  gemm_bias_cat<<<dim3(4, 128), 256, 0, stream>>>(all_h, ctx, comb_w, comb_b, keys);
  // out = combined @ fc_w^T + fc_b
  gemm_bias<0><<<dim3(2, 128), 256, 0, stream>>>(keys, 256, fc_w, fc_b, out, 100, 100, 256);
}